// Round 12
// baseline (113.129 us; speedup 1.0000x reference)
//
#include <hip/hip_runtime.h>
#include <hip/hip_bf16.h>
#include <cstdint>

// ConViT GPSA fused pipeline, bf16 MFMA throughout.
// ws (~44.9 MB): xb(7.08M) wqb/wkb/wvb/wpb(1.18M ea) Q(9.44M) K(9.44M) VT(7.08M) O(7.08M)
// posg(10.6M) overlays [xb..wvb] after gemm_qkv consumes them (wpb at 10,616,832 survives).

typedef unsigned short u16;
typedef __attribute__((ext_vector_type(8))) short bf16x8;
typedef __attribute__((ext_vector_type(4))) float f32x4;

__device__ __forceinline__ u16 f2bf(float f) {
  union { float f; uint32_t u; } v; v.f = f;
  uint32_t r = v.u + 0x7FFFu + ((v.u >> 16) & 1u);  // RNE (no NaN in this workload)
  return (u16)(r >> 16);
}
__device__ __forceinline__ float bf2f(u16 u) {
  union { uint32_t u; float f; } v; v.u = ((uint32_t)u) << 16;
  return v.f;
}

// async global->LDS, 16B per lane; LDS dest is wave-uniform base + lane*16 (linear!)
__device__ __forceinline__ void gl_lds16(const u16* g, u16* l) {
  __builtin_amdgcn_global_load_lds(
      (const __attribute__((address_space(1))) void*)g,
      (__attribute__((address_space(3))) void*)l, 16, 0, 0);
}

// Explicit-register 16B load: issued where written (volatile), dest forced live
// ("=&v") and NOT tracked by the compiler's waitcnt inserter -> all prefetch loads
// go in flight back-to-back; we wait with an explicit counted s_waitcnt.
__device__ __forceinline__ bf16x8 gload16(const u16* p) {
  bf16x8 r;
  asm volatile("global_load_dwordx4 %0, %1, off" : "=&v"(r) : "v"(p));
  return r;
}
__device__ __forceinline__ void vmwait0() {
  asm volatile("s_waitcnt vmcnt(0)");
  __builtin_amdgcn_sched_barrier(0);  // rule #18: block MFMA hoisting past the wait
}

// ---------------- f32 -> bf16: x + all 4 weights in one dispatch ----------------
__global__ __launch_bounds__(256) void cvt_all(const float* __restrict__ x,
                                               const float* __restrict__ Wq,
                                               const float* __restrict__ Wk,
                                               const float* __restrict__ Wv,
                                               const float* __restrict__ Wp,
                                               u16* __restrict__ dst) {
  const int i = blockIdx.x * 256 + threadIdx.x;  // 1,474,560 float4 items exactly
  const float* s;
  if (i < 884736) {
    s = x + (size_t)i * 4;
  } else {
    const int j = i - 884736;
    if (j < 147456) s = Wq + (size_t)j * 4;
    else if (j < 294912) s = Wk + (size_t)(j - 147456) * 4;
    else if (j < 442368) s = Wv + (size_t)(j - 294912) * 4;
    else s = Wp + (size_t)(j - 442368) * 4;
  }
  const float4 v = *(const float4*)s;
  ushort4 o;
  o.x = f2bf(v.x); o.y = f2bf(v.y); o.z = f2bf(v.z); o.w = f2bf(v.w);
  ((ushort4*)dst)[i] = o;
}

// ---------------- g-scaled positional softmax, materialized ----------------
__global__ __launch_bounds__(256) void pos_soft(const float* __restrict__ Wpos,
                                                const float* __restrict__ bpos,
                                                const float* __restrict__ gating,
                                                u16* __restrict__ posg) {
  const int w = threadIdx.x >> 6, lane = threadIdx.x & 63;
  const int row = blockIdx.x * 4 + w;            // 0..9215  (h*576+n)
  const int h = row / 576, n = row - h * 576;
  const float w0 = Wpos[h * 3 + 0], w1 = Wpos[h * 3 + 1], w2 = Wpos[h * 3 + 2], bp = bpos[h];
  const float g = 1.f / (1.f + __expf(-gating[h]));
  const int qr = n / 24, qc = n - qr * 24;
  float vals[9], evals[9];
  float mx = -1e30f;
#pragma unroll
  for (int i = 0; i < 9; ++i) {
    const int m = i * 64 + lane;
    const int kr = m / 24, kc = m - kr * 24;
    const float dx = (float)(kc - qc), dy = (float)(kr - qr);
    const float p = w0 * dx + w1 * dy + w2 * (dx * dx + dy * dy) + bp;
    vals[i] = p;
    mx = fmaxf(mx, p);
  }
#pragma unroll
  for (int off = 1; off < 64; off <<= 1) mx = fmaxf(mx, __shfl_xor(mx, off, 64));
  float s = 0.f;
#pragma unroll
  for (int i = 0; i < 9; ++i) { evals[i] = __expf(vals[i] - mx); s += evals[i]; }
#pragma unroll
  for (int off = 1; off < 64; off <<= 1) s += __shfl_xor(s, off, 64);
  const float gi = g / s;
  u16* out = posg + (size_t)row * 576;
#pragma unroll
  for (int i = 0; i < 9; ++i) out[i * 64 + lane] = f2bf(evals[i] * gi);
}

// ---------------- unified QKV projection (C = W @ x^T per mode), K = 768 ----------------
// R8 known-good config: 128x128 tile, BK=32, 2-phase double-buffered, 216x3 blocks.
// Q/K epilogue zero-fills the d48..63 head pad (lane owning d0==44 writes it).
__global__ __launch_bounds__(256, 2) void gemm_qkv(
    const u16* __restrict__ wq, const u16* __restrict__ wk, const u16* __restrict__ wv,
    const u16* __restrict__ xb, u16* __restrict__ Qo, u16* __restrict__ Ko,
    u16* __restrict__ Vo) {
  __shared__ u16 sA[2][128 * 32];  // linear, unpadded (global_load_lds dest)
  __shared__ u16 sB[2][128 * 32];

  const int y = blockIdx.y;
  const u16* A = y == 0 ? wq : y == 1 ? wk : wv;

  const int mt = blockIdx.x / 36, nt = blockIdx.x % 36;
  const int mbase = mt * 128, nbase = nt * 128;
  const int tid = threadIdx.x;
  const int w = tid >> 6, lane = tid & 63;
  const int wr = w >> 1, wc = w & 1;
  const int lg = lane >> 4, lc = lane & 15;
  const int lrow = lane >> 2;          // staging row within 16-row band
  const int lcol = (lane & 3) * 8;     // staging col (elems)

  const u16* srcA0 = A + (size_t)(mbase + w * 16 + lrow) * 768 + lcol;
  const u16* srcA1 = srcA0 + (size_t)64 * 768;
  const u16* srcB0 = xb + (size_t)(nbase + w * 16 + lrow) * 768 + lcol;
  const u16* srcB1 = srcB0 + (size_t)64 * 768;
  const int dof = w * 512;  // 16 rows * 32 elems per wave

  const f32x4 vzero = {0.f, 0.f, 0.f, 0.f};
  f32x4 acc[4][4];
#pragma unroll
  for (int i = 0; i < 4; ++i)
#pragma unroll
    for (int j = 0; j < 4; ++j) acc[i][j] = vzero;

  // prologue: stage kt=0 into buf 0
  gl_lds16(srcA0, sA[0] + dof);
  gl_lds16(srcA1, sA[0] + 2048 + dof);
  gl_lds16(srcB0, sB[0] + dof);
  gl_lds16(srcB1, sB[0] + 2048 + dof);
  __syncthreads();

  int buf = 0;
  for (int kt = 0; kt < 24; ++kt) {
    const int nb = buf ^ 1;
    if (kt < 23) {  // issue next-tile stage FIRST (latency hides under compute)
      const int kb = (kt + 1) * 32;
      gl_lds16(srcA0 + kb, sA[nb] + dof);
      gl_lds16(srcA1 + kb, sA[nb] + 2048 + dof);
      gl_lds16(srcB0 + kb, sB[nb] + dof);
      gl_lds16(srcB1 + kb, sB[nb] + 2048 + dof);
    }
    bf16x8 av[4], bv[4];
#pragma unroll
    for (int i = 0; i < 4; ++i)
      av[i] = *(const bf16x8*)&sA[buf][(wr * 64 + i * 16 + lc) * 32 + lg * 8];
#pragma unroll
    for (int jn = 0; jn < 4; ++jn)
      bv[jn] = *(const bf16x8*)&sB[buf][(wc * 64 + jn * 16 + lc) * 32 + lg * 8];
#pragma unroll
    for (int i = 0; i < 4; ++i)
#pragma unroll
      for (int jn = 0; jn < 4; ++jn)
        acc[i][jn] = __builtin_amdgcn_mfma_f32_16x16x32_bf16(av[i], bv[jn], acc[i][jn], 0, 0, 0);
    __syncthreads();  // drains vmcnt: next buf staged; all waves done reading buf
    buf = nb;
  }

  if (y < 2) {
    const float qsc = (y == 0) ? 0.14433756729740643f : 1.0f;  // 48^-0.5 folded into Q
    u16* ob = (y == 0) ? Qo : Ko;
    const float4 zf4 = {0.f, 0.f, 0.f, 0.f};
#pragma unroll
    for (int i = 0; i < 4; ++i) {
      const int c0 = mbase + wr * 64 + i * 16 + lg * 4;
      const int hh = c0 / 48;
      const int d0 = c0 - hh * 48;
      const bool padw = (d0 == 44);  // this lane also owns the row's d48..63 zero pad
#pragma unroll
      for (int jn = 0; jn < 4; ++jn) {
        const int bn = nbase + wc * 64 + jn * 16 + lc;
        const int bb = bn / 576;
        const int nn = bn - bb * 576;
        u16* rowp = &ob[(((size_t)bb * 16 + hh) * 576 + nn) * 64 + d0];
        ushort4 o;
        o.x = f2bf(acc[i][jn][0] * qsc); o.y = f2bf(acc[i][jn][1] * qsc);
        o.z = f2bf(acc[i][jn][2] * qsc); o.w = f2bf(acc[i][jn][3] * qsc);
        *(ushort4*)rowp = o;
        if (padw) {  // d0==44 -> rowp+4 is d48; write 16 zero bf16 (2x16B)
          *(float4*)(rowp + 4) = zf4;
          *(float4*)(rowp + 12) = zf4;
        }
      }
    }
  } else {
#pragma unroll
    for (int i = 0; i < 4; ++i) {
      const int c0 = mbase + wr * 64 + i * 16 + lg * 4;
      const int hh = c0 / 48;
      const int d0 = c0 - hh * 48;
#pragma unroll
      for (int jn = 0; jn < 4; ++jn) {
        const int bn = nbase + wc * 64 + jn * 16 + lc;
        const int bb = bn / 576;
        const int nn = bn - bb * 576;
#pragma unroll
        for (int j = 0; j < 4; ++j)
          Vo[(((size_t)bb * 16 + hh) * 48 + d0 + j) * 576 + nn] = f2bf(acc[i][jn][j]);
      }
    }
  }
}

// ---------------- pos-attention GEMM: Og[b,h,q,d] = sum_m V[b,m,d] * posg[h,q,m] ----------------
__global__ __launch_bounds__(256, 2) void pos_gemm(const u16* __restrict__ VT,
                                                   const u16* __restrict__ posg,
                                                   u16* __restrict__ O) {
  __shared__ u16 sA[2][128 * 32];
  __shared__ u16 sB[2][64 * 32];

  const int id = blockIdx.x;
  const int xcd = id & 7;
  const int local = id >> 3;        // 0..53
  const int h = xcd * 2 + local / 27;
  const int r = local % 27;
  const int mt = r / 9, nt = r % 9;

  const int mbase = mt * 128, nbase = nt * 64;
  const int tid = threadIdx.x;
  const int w = tid >> 6, lane = tid & 63;
  const int wr = w >> 1, wc = w & 1;
  const int lg = lane >> 4, lc = lane & 15;
  const int lrow = lane >> 2;
  const int lcol = (lane & 3) * 8;

  const int mA0 = mbase + w * 16 + lrow, mA1 = mA0 + 64;
  const u16* srcA0 = VT + ((size_t)((mA0 / 48) * 16 + h) * 48 + (mA0 % 48)) * 576 + lcol;
  const u16* srcA1 = VT + ((size_t)((mA1 / 48) * 16 + h) * 48 + (mA1 % 48)) * 576 + lcol;
  const u16* srcB0 = posg + (size_t)(h * 576 + nbase + w * 16 + lrow) * 576 + lcol;
  const int dof = w * 512;

  const f32x4 vzero = {0.f, 0.f, 0.f, 0.f};
  f32x4 acc[4][2];
#pragma unroll
  for (int i = 0; i < 4; ++i)
#pragma unroll
    for (int j = 0; j < 2; ++j) acc[i][j] = vzero;

  gl_lds16(srcA0, sA[0] + dof);
  gl_lds16(srcA1, sA[0] + 2048 + dof);
  gl_lds16(srcB0, sB[0] + dof);
  __syncthreads();

  int buf = 0;
  for (int kt = 0; kt < 18; ++kt) {
    const int nb = buf ^ 1;
    if (kt < 17) {
      const int kb = (kt + 1) * 32;
      gl_lds16(srcA0 + kb, sA[nb] + dof);
      gl_lds16(srcA1 + kb, sA[nb] + 2048 + dof);
      gl_lds16(srcB0 + kb, sB[nb] + dof);
    }
    bf16x8 av[4], bv[2];
#pragma unroll
    for (int i = 0; i < 4; ++i)
      av[i] = *(const bf16x8*)&sA[buf][(wr * 64 + i * 16 + lc) * 32 + lg * 8];
#pragma unroll
    for (int jn = 0; jn < 2; ++jn)
      bv[jn] = *(const bf16x8*)&sB[buf][(wc * 32 + jn * 16 + lc) * 32 + lg * 8];
#pragma unroll
    for (int i = 0; i < 4; ++i)
#pragma unroll
      for (int jn = 0; jn < 2; ++jn)
        acc[i][jn] = __builtin_amdgcn_mfma_f32_16x16x32_bf16(av[i], bv[jn], acc[i][jn], 0, 0, 0);
    __syncthreads();
    buf = nb;
  }

#pragma unroll
  for (int i = 0; i < 4; ++i) {
    const int c0 = mbase + wr * 64 + i * 16 + lg * 4;  // (b,d): 4 consecutive d in one head
    const int bb = c0 / 48;
    const int d0 = c0 - bb * 48;
#pragma unroll
    for (int jn = 0; jn < 2; ++jn) {
      const int q = nbase + wc * 32 + jn * 16 + lc;
      ushort4 o;
      o.x = f2bf(acc[i][jn][0]); o.y = f2bf(acc[i][jn][1]);
      o.z = f2bf(acc[i][jn][2]); o.w = f2bf(acc[i][jn][3]);
      *(ushort4*)&O[((size_t)(bb * 576 + q)) * 768 + h * 48 + d0] = o;
    }
  }
}

// ---------------- fused patch attention (pos part pre-added in Ow) ----------------
// 96 queries/block (wave = 3 x 16q subtiles); grid 768 = 8 XCD x 96.
// K/V prefetch via inline-asm loads into forced-live registers + one explicit
// s_waitcnt vmcnt(0) per chunk: all 7 loads in flight simultaneously (the compiler
// at VGPR=64 was serializing them -> ~5 latencies/chunk, the R3-R10 invariant).
__global__ __launch_bounds__(256, 2) void attn_fused(
    const u16* __restrict__ Q, const u16* __restrict__ K, const u16* __restrict__ VT,
    const float* __restrict__ gating, u16* __restrict__ O) {
  const int id = blockIdx.x;
  const int b = id & 7;             // XCD-aligned (round-robin dispatch)
  const int local = id >> 3;        // 0..95
  const int h = local / 6;
  const int qt = local % 6;
  const int tid = threadIdx.x;
  const int w = tid >> 6, lane = tid & 63;
  const int qh = w >> 1, ks = w & 1;
  const int lg = lane >> 4, lc = lane & 15;
  const int bh = b * 16 + h;

  const u16* Qh = Q + (size_t)bh * 576 * 64;
  const u16* Kh = K + (size_t)bh * 576 * 64;
  const u16* Vh = VT + (size_t)bh * 48 * 576;

  __shared__ float red[6][64][13];    // split-k: [qh*3+qs][lane][12 acc + 1 lsum]

  const bf16x8 zer = {0, 0, 0, 0, 0, 0, 0, 0};
  const int qbase = qt * 96 + qh * 48;
  // Q as B-operand: B[k=d][q=lc]; pad rows are zero -> unconditional
  bf16x8 aq[3][2];
#pragma unroll
  for (int qs = 0; qs < 3; ++qs) {
    aq[qs][0] = *(const bf16x8*)&Qh[(qbase + qs * 16 + lc) * 64 + lg * 8];
    aq[qs][1] = *(const bf16x8*)&Qh[(qbase + qs * 16 + lc) * 64 + 32 + lg * 8];
  }

  const int kbase = ks * 288;

  bf16x8 kb[2][2][2];  // [buf][t][dhalf]; A-operand: A[key-row=lc][k=d]
  bf16x8 vb[2][3];     // [buf][dt];       A-operand: A[d-row][k=key]
  // prologue: chunk 0's K in flight
#pragma unroll
  for (int t = 0; t < 2; ++t) {
    kb[0][t][0] = gload16(&Kh[(kbase + t * 16 + lc) * 64 + lg * 8]);
    kb[0][t][1] = gload16(&Kh[(kbase + t * 16 + lc) * 64 + 32 + lg * 8]);
  }
  vmwait0();

  const f32x4 vzero = {0.f, 0.f, 0.f, 0.f};
  f32x4 accP[3][3];
#pragma unroll
  for (int qs = 0; qs < 3; ++qs)
#pragma unroll
    for (int dt = 0; dt < 3; ++dt) accP[qs][dt] = vzero;
  float lsum[3] = {0.f, 0.f, 0.f};
  bf16x8 pfrag[3] = {zer, zer, zer};

  const int bpA = (((lg & 1) * 32) + lc) * 4;  // source lane byte addr (groups 0/2)
  const int bpB = bpA + 64;                    // +16 lanes (groups 1/3)
  const bool hiK = lg >= 2;                    // this lane's keys come from the s1 band

#pragma unroll
  for (int kc = 0; kc < 9; ++kc) {
    const int cur = kc & 1;
    const int k0 = kbase + kc * 32;
    // Issue ALL of this iteration's prefetches back-to-back (7 loads in flight):
    if (kc < 8) {  // K for chunk kc+1
      const int k1 = k0 + 32;
#pragma unroll
      for (int t = 0; t < 2; ++t) {
        kb[cur ^ 1][t][0] = gload16(&Kh[(k1 + t * 16 + lc) * 64 + lg * 8]);
        kb[cur ^ 1][t][1] = gload16(&Kh[(k1 + t * 16 + lc) * 64 + 32 + lg * 8]);
      }
    }
    // V for chunk kc (consumed next iteration's PV)
    vb[cur][0] = gload16(&Vh[lc * 576 + k0 + lg * 8]);
    vb[cur][1] = gload16(&Vh[(16 + lc) * 576 + k0 + lg * 8]);
    vb[cur][2] = gload16(&Vh[(32 + lc) * 576 + k0 + lg * 8]);

    // S^T[key][q=lc] per subtile, on chunk kc's K (waited last iteration)
    f32x4 s0[3], s1[3];
#pragma unroll
    for (int qs = 0; qs < 3; ++qs) {
      f32x4 a = vzero, c = vzero;
      a = __builtin_amdgcn_mfma_f32_16x16x32_bf16(kb[cur][0][0], aq[qs][0], a, 0, 0, 0);
      a = __builtin_amdgcn_mfma_f32_16x16x32_bf16(kb[cur][0][1], aq[qs][1], a, 0, 0, 0);
      c = __builtin_amdgcn_mfma_f32_16x16x32_bf16(kb[cur][1][0], aq[qs][0], c, 0, 0, 0);
      c = __builtin_amdgcn_mfma_f32_16x16x32_bf16(kb[cur][1][1], aq[qs][1], c, 0, 0, 0);
      s0[qs] = a; s1[qs] = c;
    }

    if (kc > 0) {  // PV of previous chunk (V in vb[cur^1], waited last iteration)
#pragma unroll
      for (int qs = 0; qs < 3; ++qs) {
        accP[qs][0] = __builtin_amdgcn_mfma_f32_16x16x32_bf16(vb[cur ^ 1][0], pfrag[qs], accP[qs][0], 0, 0, 0);
        accP[qs][1] = __builtin_amdgcn_mfma_f32_16x16x32_bf16(vb[cur ^ 1][1], pfrag[qs], accP[qs][1], 0, 0, 0);
        accP[qs][2] = __builtin_amdgcn_mfma_f32_16x16x32_bf16(vb[cur ^ 1][2], pfrag[qs], accP[qs][2], 0, 0, 0);
      }
    }

#pragma unroll
    for (int qs = 0; qs < 3; ++qs) {
      const float p00 = __expf(s0[qs][0]), p01 = __expf(s0[qs][1]);
      const float p02 = __expf(s0[qs][2]), p03 = __expf(s0[qs][3]);
      const float p10 = __expf(s1[qs][0]), p11 = __expf(s1[qs][1]);
      const float p12 = __expf(s1[qs][2]), p13 = __expf(s1[qs][3]);
      lsum[qs] += ((p00 + p01) + (p02 + p03)) + ((p10 + p11) + (p12 + p13));

      uint32_t c0, c1, d0, d1;  // packed bf16 pairs: c = s0-band keys, d = s1-band keys
      asm("v_cvt_pk_bf16_f32 %0, %1, %2" : "=v"(c0) : "v"(p00), "v"(p01));
      asm("v_cvt_pk_bf16_f32 %0, %1, %2" : "=v"(c1) : "v"(p02), "v"(p03));
      asm("v_cvt_pk_bf16_f32 %0, %1, %2" : "=v"(d0) : "v"(p10), "v"(p11));
      asm("v_cvt_pk_bf16_f32 %0, %1, %2" : "=v"(d1) : "v"(p12), "v"(p13));

      // Redistribute: dest lane (lg,lc) needs keys lg*8..lg*8+7 of query lc.
      const int a_c0 = __builtin_amdgcn_ds_bpermute(bpA, (int)c0);
      const int a_c1 = __builtin_amdgcn_ds_bpermute(bpA, (int)c1);
      const int a_d0 = __builtin_amdgcn_ds_bpermute(bpA, (int)d0);
      const int a_d1 = __builtin_amdgcn_ds_bpermute(bpA, (int)d1);
      const int b_c0 = __builtin_amdgcn_ds_bpermute(bpB, (int)c0);
      const int b_c1 = __builtin_amdgcn_ds_bpermute(bpB, (int)c1);
      const int b_d0 = __builtin_amdgcn_ds_bpermute(bpB, (int)d0);
      const int b_d1 = __builtin_amdgcn_ds_bpermute(bpB, (int)d1);
      union { uint32_t u[4]; bf16x8 v; } pf;
      pf.u[0] = hiK ? a_d0 : a_c0;
      pf.u[1] = hiK ? a_d1 : a_c1;
      pf.u[2] = hiK ? b_d0 : b_c0;
      pf.u[3] = hiK ? b_d1 : b_c1;
      pfrag[qs] = pf.v;
    }
    // wait for this iteration's prefetches (next iteration consumes them)
    vmwait0();
  }
  // final PV: chunk 8's V is vb[8&1] = vb[0]
#pragma unroll
  for (int qs = 0; qs < 3; ++qs) {
    accP[qs][0] = __builtin_amdgcn_mfma_f32_16x16x32_bf16(vb[0][0], pfrag[qs], accP[qs][0], 0, 0, 0);
    accP[qs][1] = __builtin_amdgcn_mfma_f32_16x16x32_bf16(vb[0][1], pfrag[qs], accP[qs][1], 0, 0, 0);
    accP[qs][2] = __builtin_amdgcn_mfma_f32_16x16x32_bf16(vb[0][2], pfrag[qs], accP[qs][2], 0, 0, 0);
  }

  // per-query (lc) row-sum for this k-half: reduce across the 4 lane-groups
  float ls[3];
#pragma unroll
  for (int qs = 0; qs < 3; ++qs) {
    float t = lsum[qs];
    t += __shfl_xor(t, 16, 64);
    t += __shfl_xor(t, 32, 64);
    ls[qs] = t;
  }

  if (ks == 1) {
#pragma unroll
    for (int qs = 0; qs < 3; ++qs) {
#pragma unroll
      for (int j = 0; j < 4; ++j) {
        red[qh * 3 + qs][lane][0 + j] = accP[qs][0][j];
        red[qh * 3 + qs][lane][4 + j] = accP[qs][1][j];
        red[qh * 3 + qs][lane][8 + j] = accP[qs][2][j];
      }
      red[qh * 3 + qs][lane][12] = ls[qs];
    }
  }
  __syncthreads();
  if (ks == 0) {
    const float g = 1.f / (1.f + __expf(-gating[h]));
#pragma unroll
    for (int qs = 0; qs < 3; ++qs) {
      const float linv = (1.f - g) / (ls[qs] + red[qh * 3 + qs][lane][12]);
      const int row = b * 576 + qbase + qs * 16 + lc;
#pragma unroll
      for (int dt = 0; dt < 3; ++dt) {
        const f32x4 a = accP[qs][dt];
        const size_t idx = (size_t)row * 768 + h * 48 + dt * 16 + lg * 4;
        const ushort4 old4 = *(const ushort4*)&O[idx];
        ushort4 o;
        o.x = f2bf((a[0] + red[qh * 3 + qs][lane][dt * 4 + 0]) * linv + bf2f(old4.x));
        o.y = f2bf((a[1] + red[qh * 3 + qs][lane][dt * 4 + 1]) * linv + bf2f(old4.y));
        o.z = f2bf((a[2] + red[qh * 3 + qs][lane][dt * 4 + 2]) * linv + bf2f(old4.z));
        o.w = f2bf((a[3] + red[qh * 3 + qs][lane][dt * 4 + 3]) * linv + bf2f(old4.w));
        *(ushort4*)&O[idx] = o;
      }
    }
  }
}

// ---------------- output projection: out = O @ Wproj^T + b ----------------
__global__ __launch_bounds__(256, 2) void gemm_proj(const u16* __restrict__ A,
                                                    const u16* __restrict__ B,
                                                    float* __restrict__ of,
                                                    const float* __restrict__ bias) {
  __shared__ u16 sA[2][128 * 32];
  __shared__ u16 sB[2][64 * 32];

  const int mt = blockIdx.x / 72, nt = blockIdx.x % 72;
  const int mbase = mt * 128, nbase = nt * 64;
  const int tid = threadIdx.x;
  const int w = tid >> 6, lane = tid & 63;
  const int wr = w >> 1, wc = w & 1;
  const int lg = lane >> 4, lc = lane & 15;
  const int lrow = lane >> 2;
  const int lcol = (lane & 3) * 8;

  const u16* srcA0 = A + (size_t)(mbase + w * 16 + lrow) * 768 + lcol;
  const u16* srcA1 = srcA0 + (size_t)64 * 768;
  const u16* srcB0 = B + (size_t)(nbase + w * 16 + lrow) * 768 + lcol;
  const int dof = w * 512;

  const f32x4 vzero = {0.f, 0.f, 0.f, 0.f};
  f32x4 acc[4][2];
#pragma unroll
  for (int i = 0; i < 4; ++i)
#pragma unroll
    for (int j = 0; j < 2; ++j) acc[i][j] = vzero;

  gl_lds16(srcA0, sA[0] + dof);
  gl_lds16(srcA1, sA[0] + 2048 + dof);
  gl_lds16(srcB0, sB[0] + dof);
  __syncthreads();

  int buf = 0;
  for (int kt = 0; kt < 24; ++kt) {
    const int nb = buf ^ 1;
    if (kt < 23) {
      const int kb = (kt + 1) * 32;
      gl_lds16(srcA0 + kb, sA[nb] + dof);
      gl_lds16(srcA1 + kb, sA[nb] + 2048 + dof);
      gl_lds16(srcB0 + kb, sB[nb] + dof);
    }
    bf16x8 av[4], bv[2];
#pragma unroll
    for (int i = 0; i < 4; ++i)
      av[i] = *(const bf16x8*)&sA[buf][(wr * 64 + i * 16 + lc) * 32 + lg * 8];
#pragma unroll
    for (int jn = 0; jn < 2; ++jn)
      bv[jn] = *(const bf16x8*)&sB[buf][(wc * 32 + jn * 16 + lc) * 32 + lg * 8];
#pragma unroll
    for (int i = 0; i < 4; ++i)
#pragma unroll
      for (int jn = 0; jn < 2; ++jn)
        acc[i][jn] = __builtin_amdgcn_mfma_f32_16x16x32_bf16(av[i], bv[jn], acc[i][jn], 0, 0, 0);
    __syncthreads();
    buf = nb;
  }

#pragma unroll
  for (int i = 0; i < 4; ++i) {
    const int c0 = mbase + wr * 64 + i * 16 + lg * 4;
    const float4 b4 = *(const float4*)&bias[c0];
#pragma unroll
    for (int jn = 0; jn < 2; ++jn) {
      const int bn = nbase + wc * 32 + jn * 16 + lc;
      float4 o;
      o.x = acc[i][jn][0] + b4.x; o.y = acc[i][jn][1] + b4.y;
      o.z = acc[i][jn][2] + b4.z; o.w = acc[i][jn][3] + b4.w;
      *(float4*)&of[(size_t)bn * 768 + c0] = o;
    }
  }
}

// ---------------- launch ----------------
extern "C" void kernel_launch(void* const* d_in, const int* in_sizes, int n_in,
                              void* d_out, int out_size, void* d_ws, size_t ws_size,
                              hipStream_t stream) {
  const float* x      = (const float*)d_in[0];
  const float* Wq     = (const float*)d_in[1];
  const float* Wk     = (const float*)d_in[2];
  const float* Wv     = (const float*)d_in[3];
  const float* Wp     = (const float*)d_in[4];
  const float* bproj  = (const float*)d_in[5];
  const float* Wpos   = (const float*)d_in[6];
  const float* bpos   = (const float*)d_in[7];
  const float* gating = (const float*)d_in[8];
  float* out = (float*)d_out;

  char* ws = (char*)d_ws;
  u16* xb   = (u16*)(ws + 0);
  u16* wqb  = (u16*)(ws + 7077888);
  u16* wkb  = (u16*)(ws + 8257536);
  u16* wvb  = (u16*)(ws + 9437184);
  u16* wpb  = (u16*)(ws + 10616832);
  u16* Qw   = (u16*)(ws + 11796480);
  u16* Kw   = (u16*)(ws + 21233664);
  u16* VTw  = (u16*)(ws + 30670848);
  u16* Ow   = (u16*)(ws + 37748736);
  u16* posg = (u16*)(ws + 0);  // overlays xb..wvb (dead after gemm_qkv); ends exactly at wpb

  cvt_all<<<dim3(5760), dim3(256), 0, stream>>>(x, Wq, Wk, Wv, Wp, xb);
  gemm_qkv<<<dim3(216, 3), dim3(256), 0, stream>>>(wqb, wkb, wvb, xb, Qw, Kw, VTw);
  pos_soft<<<dim3(2304), dim3(256), 0, stream>>>(Wpos, bpos, gating, posg);
  pos_gemm<<<dim3(432), dim3(256), 0, stream>>>(VTw, posg, Ow);
  attn_fused<<<dim3(768), dim3(256), 0, stream>>>(Qw, Kw, VTw, gating, Ow);
  gemm_proj<<<dim3(432), dim3(256), 0, stream>>>(wpb, Ow, out, bproj);
}

// Round 13
// 112.874 us; speedup vs baseline: 1.0023x; 1.0023x over previous
//
#include <hip/hip_runtime.h>
#include <hip/hip_bf16.h>
#include <cstdint>

// ConViT GPSA fused pipeline, bf16 MFMA throughout.
// ws (~44.9 MB): xb(7.08M) wqb/wkb/wvb/wpb(1.18M ea) Q(9.44M) K(9.44M) VT(7.08M) O(7.08M)
// posg(10.6M) overlays [xb..wvb] after gemm_qkv consumes them (wpb at 10,616,832 survives).

typedef unsigned short u16;
typedef __attribute__((ext_vector_type(8))) short bf16x8;
typedef __attribute__((ext_vector_type(4))) float f32x4;

__device__ __forceinline__ u16 f2bf(float f) {
  union { float f; uint32_t u; } v; v.f = f;
  uint32_t r = v.u + 0x7FFFu + ((v.u >> 16) & 1u);  // RNE (no NaN in this workload)
  return (u16)(r >> 16);
}
__device__ __forceinline__ float bf2f(u16 u) {
  union { uint32_t u; float f; } v; v.u = ((uint32_t)u) << 16;
  return v.f;
}

// async global->LDS, 16B per lane; LDS dest is wave-uniform base + lane*16 (linear!)
__device__ __forceinline__ void gl_lds16(const u16* g, u16* l) {
  __builtin_amdgcn_global_load_lds(
      (const __attribute__((address_space(1))) void*)g,
      (__attribute__((address_space(3))) void*)l, 16, 0, 0);
}

// Explicit-register 16B load: issued where written (volatile), dest forced live
// ("=&v") and NOT tracked by the compiler's waitcnt inserter -> all prefetch loads
// go in flight back-to-back; we wait with an explicit counted s_waitcnt.
__device__ __forceinline__ bf16x8 gload16(const u16* p) {
  bf16x8 r;
  asm volatile("global_load_dwordx4 %0, %1, off" : "=&v"(r) : "v"(p));
  return r;
}
__device__ __forceinline__ void vmwait0() {
  asm volatile("s_waitcnt vmcnt(0)");
  __builtin_amdgcn_sched_barrier(0);  // rule #18: block MFMA hoisting past the wait
}

// ---------------- f32 -> bf16: x + all 4 weights in one dispatch ----------------
__global__ __launch_bounds__(256) void cvt_all(const float* __restrict__ x,
                                               const float* __restrict__ Wq,
                                               const float* __restrict__ Wk,
                                               const float* __restrict__ Wv,
                                               const float* __restrict__ Wp,
                                               u16* __restrict__ dst) {
  const int i = blockIdx.x * 256 + threadIdx.x;  // 1,474,560 float4 items exactly
  const float* s;
  if (i < 884736) {
    s = x + (size_t)i * 4;
  } else {
    const int j = i - 884736;
    if (j < 147456) s = Wq + (size_t)j * 4;
    else if (j < 294912) s = Wk + (size_t)(j - 147456) * 4;
    else if (j < 442368) s = Wv + (size_t)(j - 294912) * 4;
    else s = Wp + (size_t)(j - 442368) * 4;
  }
  const float4 v = *(const float4*)s;
  ushort4 o;
  o.x = f2bf(v.x); o.y = f2bf(v.y); o.z = f2bf(v.z); o.w = f2bf(v.w);
  ((ushort4*)dst)[i] = o;
}

// ---------------- g-scaled positional softmax, materialized ----------------
__global__ __launch_bounds__(256) void pos_soft(const float* __restrict__ Wpos,
                                                const float* __restrict__ bpos,
                                                const float* __restrict__ gating,
                                                u16* __restrict__ posg) {
  const int w = threadIdx.x >> 6, lane = threadIdx.x & 63;
  const int row = blockIdx.x * 4 + w;            // 0..9215  (h*576+n)
  const int h = row / 576, n = row - h * 576;
  const float w0 = Wpos[h * 3 + 0], w1 = Wpos[h * 3 + 1], w2 = Wpos[h * 3 + 2], bp = bpos[h];
  const float g = 1.f / (1.f + __expf(-gating[h]));
  const int qr = n / 24, qc = n - qr * 24;
  float vals[9], evals[9];
  float mx = -1e30f;
#pragma unroll
  for (int i = 0; i < 9; ++i) {
    const int m = i * 64 + lane;
    const int kr = m / 24, kc = m - kr * 24;
    const float dx = (float)(kc - qc), dy = (float)(kr - qr);
    const float p = w0 * dx + w1 * dy + w2 * (dx * dx + dy * dy) + bp;
    vals[i] = p;
    mx = fmaxf(mx, p);
  }
#pragma unroll
  for (int off = 1; off < 64; off <<= 1) mx = fmaxf(mx, __shfl_xor(mx, off, 64));
  float s = 0.f;
#pragma unroll
  for (int i = 0; i < 9; ++i) { evals[i] = __expf(vals[i] - mx); s += evals[i]; }
#pragma unroll
  for (int off = 1; off < 64; off <<= 1) s += __shfl_xor(s, off, 64);
  const float gi = g / s;
  u16* out = posg + (size_t)row * 576;
#pragma unroll
  for (int i = 0; i < 9; ++i) out[i * 64 + lane] = f2bf(evals[i] * gi);
}

// ---------------- unified QKV projection (C = W @ x^T per mode), K = 768 ----------------
// R8 known-good config: 128x128 tile, BK=32, 2-phase double-buffered, 216x3 blocks.
// Q/K epilogue zero-fills the d48..63 head pad (lane owning d0==44 writes it).
__global__ __launch_bounds__(256, 2) void gemm_qkv(
    const u16* __restrict__ wq, const u16* __restrict__ wk, const u16* __restrict__ wv,
    const u16* __restrict__ xb, u16* __restrict__ Qo, u16* __restrict__ Ko,
    u16* __restrict__ Vo) {
  __shared__ u16 sA[2][128 * 32];  // linear, unpadded (global_load_lds dest)
  __shared__ u16 sB[2][128 * 32];

  const int y = blockIdx.y;
  const u16* A = y == 0 ? wq : y == 1 ? wk : wv;

  const int mt = blockIdx.x / 36, nt = blockIdx.x % 36;
  const int mbase = mt * 128, nbase = nt * 128;
  const int tid = threadIdx.x;
  const int w = tid >> 6, lane = tid & 63;
  const int wr = w >> 1, wc = w & 1;
  const int lg = lane >> 4, lc = lane & 15;
  const int lrow = lane >> 2;          // staging row within 16-row band
  const int lcol = (lane & 3) * 8;     // staging col (elems)

  const u16* srcA0 = A + (size_t)(mbase + w * 16 + lrow) * 768 + lcol;
  const u16* srcA1 = srcA0 + (size_t)64 * 768;
  const u16* srcB0 = xb + (size_t)(nbase + w * 16 + lrow) * 768 + lcol;
  const u16* srcB1 = srcB0 + (size_t)64 * 768;
  const int dof = w * 512;  // 16 rows * 32 elems per wave

  const f32x4 vzero = {0.f, 0.f, 0.f, 0.f};
  f32x4 acc[4][4];
#pragma unroll
  for (int i = 0; i < 4; ++i)
#pragma unroll
    for (int j = 0; j < 4; ++j) acc[i][j] = vzero;

  // prologue: stage kt=0 into buf 0
  gl_lds16(srcA0, sA[0] + dof);
  gl_lds16(srcA1, sA[0] + 2048 + dof);
  gl_lds16(srcB0, sB[0] + dof);
  gl_lds16(srcB1, sB[0] + 2048 + dof);
  __syncthreads();

  int buf = 0;
  for (int kt = 0; kt < 24; ++kt) {
    const int nb = buf ^ 1;
    if (kt < 23) {  // issue next-tile stage FIRST (latency hides under compute)
      const int kb = (kt + 1) * 32;
      gl_lds16(srcA0 + kb, sA[nb] + dof);
      gl_lds16(srcA1 + kb, sA[nb] + 2048 + dof);
      gl_lds16(srcB0 + kb, sB[nb] + dof);
      gl_lds16(srcB1 + kb, sB[nb] + 2048 + dof);
    }
    bf16x8 av[4], bv[4];
#pragma unroll
    for (int i = 0; i < 4; ++i)
      av[i] = *(const bf16x8*)&sA[buf][(wr * 64 + i * 16 + lc) * 32 + lg * 8];
#pragma unroll
    for (int jn = 0; jn < 4; ++jn)
      bv[jn] = *(const bf16x8*)&sB[buf][(wc * 64 + jn * 16 + lc) * 32 + lg * 8];
#pragma unroll
    for (int i = 0; i < 4; ++i)
#pragma unroll
      for (int jn = 0; jn < 4; ++jn)
        acc[i][jn] = __builtin_amdgcn_mfma_f32_16x16x32_bf16(av[i], bv[jn], acc[i][jn], 0, 0, 0);
    __syncthreads();  // drains vmcnt: next buf staged; all waves done reading buf
    buf = nb;
  }

  if (y < 2) {
    const float qsc = (y == 0) ? 0.14433756729740643f : 1.0f;  // 48^-0.5 folded into Q
    u16* ob = (y == 0) ? Qo : Ko;
    const float4 zf4 = {0.f, 0.f, 0.f, 0.f};
#pragma unroll
    for (int i = 0; i < 4; ++i) {
      const int c0 = mbase + wr * 64 + i * 16 + lg * 4;
      const int hh = c0 / 48;
      const int d0 = c0 - hh * 48;
      const bool padw = (d0 == 44);  // this lane also owns the row's d48..63 zero pad
#pragma unroll
      for (int jn = 0; jn < 4; ++jn) {
        const int bn = nbase + wc * 64 + jn * 16 + lc;
        const int bb = bn / 576;
        const int nn = bn - bb * 576;
        u16* rowp = &ob[(((size_t)bb * 16 + hh) * 576 + nn) * 64 + d0];
        ushort4 o;
        o.x = f2bf(acc[i][jn][0] * qsc); o.y = f2bf(acc[i][jn][1] * qsc);
        o.z = f2bf(acc[i][jn][2] * qsc); o.w = f2bf(acc[i][jn][3] * qsc);
        *(ushort4*)rowp = o;
        if (padw) {  // d0==44 -> rowp+4 is d48; write 16 zero bf16 (2x16B)
          *(float4*)(rowp + 4) = zf4;
          *(float4*)(rowp + 12) = zf4;
        }
      }
    }
  } else {
#pragma unroll
    for (int i = 0; i < 4; ++i) {
      const int c0 = mbase + wr * 64 + i * 16 + lg * 4;
      const int hh = c0 / 48;
      const int d0 = c0 - hh * 48;
#pragma unroll
      for (int jn = 0; jn < 4; ++jn) {
        const int bn = nbase + wc * 64 + jn * 16 + lc;
        const int bb = bn / 576;
        const int nn = bn - bb * 576;
#pragma unroll
        for (int j = 0; j < 4; ++j)
          Vo[(((size_t)bb * 16 + hh) * 48 + d0 + j) * 576 + nn] = f2bf(acc[i][jn][j]);
      }
    }
  }
}

// ---------------- pos-attention GEMM: Og[b,h,q,d] = sum_m V[b,m,d] * posg[h,q,m] ----------------
__global__ __launch_bounds__(256, 2) void pos_gemm(const u16* __restrict__ VT,
                                                   const u16* __restrict__ posg,
                                                   u16* __restrict__ O) {
  __shared__ u16 sA[2][128 * 32];
  __shared__ u16 sB[2][64 * 32];

  const int id = blockIdx.x;
  const int xcd = id & 7;
  const int local = id >> 3;        // 0..53
  const int h = xcd * 2 + local / 27;
  const int r = local % 27;
  const int mt = r / 9, nt = r % 9;

  const int mbase = mt * 128, nbase = nt * 64;
  const int tid = threadIdx.x;
  const int w = tid >> 6, lane = tid & 63;
  const int wr = w >> 1, wc = w & 1;
  const int lg = lane >> 4, lc = lane & 15;
  const int lrow = lane >> 2;
  const int lcol = (lane & 3) * 8;

  const int mA0 = mbase + w * 16 + lrow, mA1 = mA0 + 64;
  const u16* srcA0 = VT + ((size_t)((mA0 / 48) * 16 + h) * 48 + (mA0 % 48)) * 576 + lcol;
  const u16* srcA1 = VT + ((size_t)((mA1 / 48) * 16 + h) * 48 + (mA1 % 48)) * 576 + lcol;
  const u16* srcB0 = posg + (size_t)(h * 576 + nbase + w * 16 + lrow) * 576 + lcol;
  const int dof = w * 512;

  const f32x4 vzero = {0.f, 0.f, 0.f, 0.f};
  f32x4 acc[4][2];
#pragma unroll
  for (int i = 0; i < 4; ++i)
#pragma unroll
    for (int j = 0; j < 2; ++j) acc[i][j] = vzero;

  gl_lds16(srcA0, sA[0] + dof);
  gl_lds16(srcA1, sA[0] + 2048 + dof);
  gl_lds16(srcB0, sB[0] + dof);
  __syncthreads();

  int buf = 0;
  for (int kt = 0; kt < 18; ++kt) {
    const int nb = buf ^ 1;
    if (kt < 17) {
      const int kb = (kt + 1) * 32;
      gl_lds16(srcA0 + kb, sA[nb] + dof);
      gl_lds16(srcA1 + kb, sA[nb] + 2048 + dof);
      gl_lds16(srcB0 + kb, sB[nb] + dof);
    }
    bf16x8 av[4], bv[2];
#pragma unroll
    for (int i = 0; i < 4; ++i)
      av[i] = *(const bf16x8*)&sA[buf][(wr * 64 + i * 16 + lc) * 32 + lg * 8];
#pragma unroll
    for (int jn = 0; jn < 2; ++jn)
      bv[jn] = *(const bf16x8*)&sB[buf][(wc * 32 + jn * 16 + lc) * 32 + lg * 8];
#pragma unroll
    for (int i = 0; i < 4; ++i)
#pragma unroll
      for (int jn = 0; jn < 2; ++jn)
        acc[i][jn] = __builtin_amdgcn_mfma_f32_16x16x32_bf16(av[i], bv[jn], acc[i][jn], 0, 0, 0);
    __syncthreads();
    buf = nb;
  }

#pragma unroll
  for (int i = 0; i < 4; ++i) {
    const int c0 = mbase + wr * 64 + i * 16 + lg * 4;  // (b,d): 4 consecutive d in one head
    const int bb = c0 / 48;
    const int d0 = c0 - bb * 48;
#pragma unroll
    for (int jn = 0; jn < 2; ++jn) {
      const int q = nbase + wc * 32 + jn * 16 + lc;
      ushort4 o;
      o.x = f2bf(acc[i][jn][0]); o.y = f2bf(acc[i][jn][1]);
      o.z = f2bf(acc[i][jn][2]); o.w = f2bf(acc[i][jn][3]);
      *(ushort4*)&O[((size_t)(bb * 576 + q)) * 768 + h * 48 + d0] = o;
    }
  }
}

// ---------------- fused patch attention (pos part pre-added in Ow) ----------------
// 96 queries/block (wave = 3 x 16q subtiles); grid 768 = 8 XCD x 96.
// K/V prefetch via inline-asm loads into forced-live registers + one explicit
// s_waitcnt vmcnt(0) per chunk: all 7 loads in flight simultaneously (the compiler
// at VGPR=64 was serializing them -> ~5 latencies/chunk, the R3-R10 invariant).
__global__ __launch_bounds__(256, 2) void attn_fused(
    const u16* __restrict__ Q, const u16* __restrict__ K, const u16* __restrict__ VT,
    const float* __restrict__ gating, u16* __restrict__ O) {
  const int id = blockIdx.x;
  const int b = id & 7;             // XCD-aligned (round-robin dispatch)
  const int local = id >> 3;        // 0..95
  const int h = local / 6;
  const int qt = local % 6;
  const int tid = threadIdx.x;
  const int w = tid >> 6, lane = tid & 63;
  const int qh = w >> 1, ks = w & 1;
  const int lg = lane >> 4, lc = lane & 15;
  const int bh = b * 16 + h;

  const u16* Qh = Q + (size_t)bh * 576 * 64;
  const u16* Kh = K + (size_t)bh * 576 * 64;
  const u16* Vh = VT + (size_t)bh * 48 * 576;

  __shared__ float red[6][64][13];    // split-k: [qh*3+qs][lane][12 acc + 1 lsum]

  const bf16x8 zer = {0, 0, 0, 0, 0, 0, 0, 0};
  const int qbase = qt * 96 + qh * 48;
  // Q as B-operand: B[k=d][q=lc]; pad rows are zero -> unconditional
  bf16x8 aq[3][2];
#pragma unroll
  for (int qs = 0; qs < 3; ++qs) {
    aq[qs][0] = *(const bf16x8*)&Qh[(qbase + qs * 16 + lc) * 64 + lg * 8];
    aq[qs][1] = *(const bf16x8*)&Qh[(qbase + qs * 16 + lc) * 64 + 32 + lg * 8];
  }

  const int kbase = ks * 288;

  bf16x8 kb[2][2][2];  // [buf][t][dhalf]; A-operand: A[key-row=lc][k=d]
  bf16x8 vb[2][3];     // [buf][dt];       A-operand: A[d-row][k=key]
  // prologue: chunk 0's K in flight
#pragma unroll
  for (int t = 0; t < 2; ++t) {
    kb[0][t][0] = gload16(&Kh[(kbase + t * 16 + lc) * 64 + lg * 8]);
    kb[0][t][1] = gload16(&Kh[(kbase + t * 16 + lc) * 64 + 32 + lg * 8]);
  }
  vmwait0();

  const f32x4 vzero = {0.f, 0.f, 0.f, 0.f};
  f32x4 accP[3][3];
#pragma unroll
  for (int qs = 0; qs < 3; ++qs)
#pragma unroll
    for (int dt = 0; dt < 3; ++dt) accP[qs][dt] = vzero;
  float lsum[3] = {0.f, 0.f, 0.f};
  bf16x8 pfrag[3] = {zer, zer, zer};

  const int bpA = (((lg & 1) * 32) + lc) * 4;  // source lane byte addr (groups 0/2)
  const int bpB = bpA + 64;                    // +16 lanes (groups 1/3)
  const bool hiK = lg >= 2;                    // this lane's keys come from the s1 band

#pragma unroll
  for (int kc = 0; kc < 9; ++kc) {
    const int cur = kc & 1;
    const int k0 = kbase + kc * 32;
    // Issue ALL of this iteration's prefetches back-to-back (7 loads in flight):
    if (kc < 8) {  // K for chunk kc+1
      const int k1 = k0 + 32;
#pragma unroll
      for (int t = 0; t < 2; ++t) {
        kb[cur ^ 1][t][0] = gload16(&Kh[(k1 + t * 16 + lc) * 64 + lg * 8]);
        kb[cur ^ 1][t][1] = gload16(&Kh[(k1 + t * 16 + lc) * 64 + 32 + lg * 8]);
      }
    }
    // V for chunk kc (consumed next iteration's PV)
    vb[cur][0] = gload16(&Vh[lc * 576 + k0 + lg * 8]);
    vb[cur][1] = gload16(&Vh[(16 + lc) * 576 + k0 + lg * 8]);
    vb[cur][2] = gload16(&Vh[(32 + lc) * 576 + k0 + lg * 8]);

    // S^T[key][q=lc] per subtile, on chunk kc's K (waited last iteration)
    f32x4 s0[3], s1[3];
#pragma unroll
    for (int qs = 0; qs < 3; ++qs) {
      f32x4 a = vzero, c = vzero;
      a = __builtin_amdgcn_mfma_f32_16x16x32_bf16(kb[cur][0][0], aq[qs][0], a, 0, 0, 0);
      a = __builtin_amdgcn_mfma_f32_16x16x32_bf16(kb[cur][0][1], aq[qs][1], a, 0, 0, 0);
      c = __builtin_amdgcn_mfma_f32_16x16x32_bf16(kb[cur][1][0], aq[qs][0], c, 0, 0, 0);
      c = __builtin_amdgcn_mfma_f32_16x16x32_bf16(kb[cur][1][1], aq[qs][1], c, 0, 0, 0);
      s0[qs] = a; s1[qs] = c;
    }

    if (kc > 0) {  // PV of previous chunk (V in vb[cur^1], waited last iteration)
#pragma unroll
      for (int qs = 0; qs < 3; ++qs) {
        accP[qs][0] = __builtin_amdgcn_mfma_f32_16x16x32_bf16(vb[cur ^ 1][0], pfrag[qs], accP[qs][0], 0, 0, 0);
        accP[qs][1] = __builtin_amdgcn_mfma_f32_16x16x32_bf16(vb[cur ^ 1][1], pfrag[qs], accP[qs][1], 0, 0, 0);
        accP[qs][2] = __builtin_amdgcn_mfma_f32_16x16x32_bf16(vb[cur ^ 1][2], pfrag[qs], accP[qs][2], 0, 0, 0);
      }
    }

#pragma unroll
    for (int qs = 0; qs < 3; ++qs) {
      const float p00 = __expf(s0[qs][0]), p01 = __expf(s0[qs][1]);
      const float p02 = __expf(s0[qs][2]), p03 = __expf(s0[qs][3]);
      const float p10 = __expf(s1[qs][0]), p11 = __expf(s1[qs][1]);
      const float p12 = __expf(s1[qs][2]), p13 = __expf(s1[qs][3]);
      lsum[qs] += ((p00 + p01) + (p02 + p03)) + ((p10 + p11) + (p12 + p13));

      uint32_t c0, c1, d0, d1;  // packed bf16 pairs: c = s0-band keys, d = s1-band keys
      asm("v_cvt_pk_bf16_f32 %0, %1, %2" : "=v"(c0) : "v"(p00), "v"(p01));
      asm("v_cvt_pk_bf16_f32 %0, %1, %2" : "=v"(c1) : "v"(p02), "v"(p03));
      asm("v_cvt_pk_bf16_f32 %0, %1, %2" : "=v"(d0) : "v"(p10), "v"(p11));
      asm("v_cvt_pk_bf16_f32 %0, %1, %2" : "=v"(d1) : "v"(p12), "v"(p13));

      // Redistribute: dest lane (lg,lc) needs keys lg*8..lg*8+7 of query lc.
      const int a_c0 = __builtin_amdgcn_ds_bpermute(bpA, (int)c0);
      const int a_c1 = __builtin_amdgcn_ds_bpermute(bpA, (int)c1);
      const int a_d0 = __builtin_amdgcn_ds_bpermute(bpA, (int)d0);
      const int a_d1 = __builtin_amdgcn_ds_bpermute(bpA, (int)d1);
      const int b_c0 = __builtin_amdgcn_ds_bpermute(bpB, (int)c0);
      const int b_c1 = __builtin_amdgcn_ds_bpermute(bpB, (int)c1);
      const int b_d0 = __builtin_amdgcn_ds_bpermute(bpB, (int)d0);
      const int b_d1 = __builtin_amdgcn_ds_bpermute(bpB, (int)d1);
      union { uint32_t u[4]; bf16x8 v; } pf;
      pf.u[0] = hiK ? a_d0 : a_c0;
      pf.u[1] = hiK ? a_d1 : a_c1;
      pf.u[2] = hiK ? b_d0 : b_c0;
      pf.u[3] = hiK ? b_d1 : b_c1;
      pfrag[qs] = pf.v;
    }
    // wait for this iteration's prefetches (next iteration consumes them)
    vmwait0();
  }
  // final PV: chunk 8's V is vb[8&1] = vb[0]
#pragma unroll
  for (int qs = 0; qs < 3; ++qs) {
    accP[qs][0] = __builtin_amdgcn_mfma_f32_16x16x32_bf16(vb[0][0], pfrag[qs], accP[qs][0], 0, 0, 0);
    accP[qs][1] = __builtin_amdgcn_mfma_f32_16x16x32_bf16(vb[0][1], pfrag[qs], accP[qs][1], 0, 0, 0);
    accP[qs][2] = __builtin_amdgcn_mfma_f32_16x16x32_bf16(vb[0][2], pfrag[qs], accP[qs][2], 0, 0, 0);
  }

  // per-query (lc) row-sum for this k-half: reduce across the 4 lane-groups
  float ls[3];
#pragma unroll
  for (int qs = 0; qs < 3; ++qs) {
    float t = lsum[qs];
    t += __shfl_xor(t, 16, 64);
    t += __shfl_xor(t, 32, 64);
    ls[qs] = t;
  }

  if (ks == 1) {
#pragma unroll
    for (int qs = 0; qs < 3; ++qs) {
#pragma unroll
      for (int j = 0; j < 4; ++j) {
        red[qh * 3 + qs][lane][0 + j] = accP[qs][0][j];
        red[qh * 3 + qs][lane][4 + j] = accP[qs][1][j];
        red[qh * 3 + qs][lane][8 + j] = accP[qs][2][j];
      }
      red[qh * 3 + qs][lane][12] = ls[qs];
    }
  }
  __syncthreads();
  if (ks == 0) {
    const float g = 1.f / (1.f + __expf(-gating[h]));
#pragma unroll
    for (int qs = 0; qs < 3; ++qs) {
      const float linv = (1.f - g) / (ls[qs] + red[qh * 3 + qs][lane][12]);
      const int row = b * 576 + qbase + qs * 16 + lc;
#pragma unroll
      for (int dt = 0; dt < 3; ++dt) {
        const f32x4 a = accP[qs][dt];
        const size_t idx = (size_t)row * 768 + h * 48 + dt * 16 + lg * 4;
        const ushort4 old4 = *(const ushort4*)&O[idx];
        ushort4 o;
        o.x = f2bf((a[0] + red[qh * 3 + qs][lane][dt * 4 + 0]) * linv + bf2f(old4.x));
        o.y = f2bf((a[1] + red[qh * 3 + qs][lane][dt * 4 + 1]) * linv + bf2f(old4.y));
        o.z = f2bf((a[2] + red[qh * 3 + qs][lane][dt * 4 + 2]) * linv + bf2f(old4.z));
        o.w = f2bf((a[3] + red[qh * 3 + qs][lane][dt * 4 + 3]) * linv + bf2f(old4.w));
        *(ushort4*)&O[idx] = o;
      }
    }
  }
}

// ---------------- output projection: out = O @ Wproj^T + b ----------------
__global__ __launch_bounds__(256, 2) void gemm_proj(const u16* __restrict__ A,
                                                    const u16* __restrict__ B,
                                                    float* __restrict__ of,
                                                    const float* __restrict__ bias) {
  __shared__ u16 sA[2][128 * 32];
  __shared__ u16 sB[2][64 * 32];

  const int mt = blockIdx.x / 72, nt = blockIdx.x % 72;
  const int mbase = mt * 128, nbase = nt * 64;
  const int tid = threadIdx.x;
  const int w = tid >> 6, lane = tid & 63;
  const int wr = w >> 1, wc = w & 1;
  const int lg = lane >> 4, lc = lane & 15;
  const int lrow = lane >> 2;
  const int lcol = (lane & 3) * 8;

  const u16* srcA0 = A + (size_t)(mbase + w * 16 + lrow) * 768 + lcol;
  const u16* srcA1 = srcA0 + (size_t)64 * 768;
  const u16* srcB0 = B + (size_t)(nbase + w * 16 + lrow) * 768 + lcol;
  const int dof = w * 512;

  const f32x4 vzero = {0.f, 0.f, 0.f, 0.f};
  f32x4 acc[4][2];
#pragma unroll
  for (int i = 0; i < 4; ++i)
#pragma unroll
    for (int j = 0; j < 2; ++j) acc[i][j] = vzero;

  gl_lds16(srcA0, sA[0] + dof);
  gl_lds16(srcA1, sA[0] + 2048 + dof);
  gl_lds16(srcB0, sB[0] + dof);
  __syncthreads();

  int buf = 0;
  for (int kt = 0; kt < 24; ++kt) {
    const int nb = buf ^ 1;
    if (kt < 23) {
      const int kb = (kt + 1) * 32;
      gl_lds16(srcA0 + kb, sA[nb] + dof);
      gl_lds16(srcA1 + kb, sA[nb] + 2048 + dof);
      gl_lds16(srcB0 + kb, sB[nb] + dof);
    }
    bf16x8 av[4], bv[2];
#pragma unroll
    for (int i = 0; i < 4; ++i)
      av[i] = *(const bf16x8*)&sA[buf][(wr * 64 + i * 16 + lc) * 32 + lg * 8];
#pragma unroll
    for (int jn = 0; jn < 2; ++jn)
      bv[jn] = *(const bf16x8*)&sB[buf][(wc * 32 + jn * 16 + lc) * 32 + lg * 8];
#pragma unroll
    for (int i = 0; i < 4; ++i)
#pragma unroll
      for (int jn = 0; jn < 2; ++jn)
        acc[i][jn] = __builtin_amdgcn_mfma_f32_16x16x32_bf16(av[i], bv[jn], acc[i][jn], 0, 0, 0);
    __syncthreads();
    buf = nb;
  }

#pragma unroll
  for (int i = 0; i < 4; ++i) {
    const int c0 = mbase + wr * 64 + i * 16 + lg * 4;
    const float4 b4 = *(const float4*)&bias[c0];
#pragma unroll
    for (int jn = 0; jn < 2; ++jn) {
      const int bn = nbase + wc * 32 + jn * 16 + lc;
      float4 o;
      o.x = acc[i][jn][0] + b4.x; o.y = acc[i][jn][1] + b4.y;
      o.z = acc[i][jn][2] + b4.z; o.w = acc[i][jn][3] + b4.w;
      *(float4*)&of[(size_t)bn * 768 + c0] = o;
    }
  }
}

// ---------------- launch ----------------
extern "C" void kernel_launch(void* const* d_in, const int* in_sizes, int n_in,
                              void* d_out, int out_size, void* d_ws, size_t ws_size,
                              hipStream_t stream) {
  const float* x      = (const float*)d_in[0];
  const float* Wq     = (const float*)d_in[1];
  const float* Wk     = (const float*)d_in[2];
  const float* Wv     = (const float*)d_in[3];
  const float* Wp     = (const float*)d_in[4];
  const float* bproj  = (const float*)d_in[5];
  const float* Wpos   = (const float*)d_in[6];
  const float* bpos   = (const float*)d_in[7];
  const float* gating = (const float*)d_in[8];
  float* out = (float*)d_out;

  char* ws = (char*)d_ws;
  u16* xb   = (u16*)(ws + 0);
  u16* wqb  = (u16*)(ws + 7077888);
  u16* wkb  = (u16*)(ws + 8257536);
  u16* wvb  = (u16*)(ws + 9437184);
  u16* wpb  = (u16*)(ws + 10616832);
  u16* Qw   = (u16*)(ws + 11796480);
  u16* Kw   = (u16*)(ws + 21233664);
  u16* VTw  = (u16*)(ws + 30670848);
  u16* Ow   = (u16*)(ws + 37748736);
  u16* posg = (u16*)(ws + 0);  // overlays xb..wvb (dead after gemm_qkv); ends exactly at wpb

  cvt_all<<<dim3(5760), dim3(256), 0, stream>>>(x, Wq, Wk, Wv, Wp, xb);
  gemm_qkv<<<dim3(216, 3), dim3(256), 0, stream>>>(wqb, wkb, wvb, xb, Qw, Kw, VTw);
  pos_soft<<<dim3(2304), dim3(256), 0, stream>>>(Wpos, bpos, gating, posg);
  pos_gemm<<<dim3(432), dim3(256), 0, stream>>>(VTw, posg, Ow);
  attn_fused<<<dim3(768), dim3(256), 0, stream>>>(Qw, Kw, VTw, gating, Ow);
  gemm_proj<<<dim3(432), dim3(256), 0, stream>>>(wpb, Ow, out, bproj);
}

// Round 14
// 110.261 us; speedup vs baseline: 1.0260x; 1.0237x over previous
//
#include <hip/hip_runtime.h>
#include <hip/hip_bf16.h>
#include <cstdint>

// ConViT GPSA fused pipeline, bf16 MFMA throughout.
// ws layout: xb(7.08M) wqb/wkb/wvb/wpb(1.18M ea) Q(9.44M) K(9.44M) VT(7.08M) O2(7.08M) O1(7.08M)
// posg(10.6M) overlays [xb..wvb] after gemm_qkv consumes them.
// Merged pos+attn dispatch needs ws >= 51,904,512 B; guarded fallback = serial R13 path.

typedef unsigned short u16;
typedef __attribute__((ext_vector_type(8))) short bf16x8;
typedef __attribute__((ext_vector_type(4))) float f32x4;

__device__ __forceinline__ u16 f2bf(float f) {
  union { float f; uint32_t u; } v; v.f = f;
  uint32_t r = v.u + 0x7FFFu + ((v.u >> 16) & 1u);  // RNE (no NaN in this workload)
  return (u16)(r >> 16);
}
__device__ __forceinline__ float bf2f(u16 u) {
  union { uint32_t u; float f; } v; v.u = ((uint32_t)u) << 16;
  return v.f;
}

__device__ __forceinline__ void gl_lds16(const u16* g, u16* l) {
  __builtin_amdgcn_global_load_lds(
      (const __attribute__((address_space(1))) void*)g,
      (__attribute__((address_space(3))) void*)l, 16, 0, 0);
}
__device__ __forceinline__ bf16x8 gload16(const u16* p) {
  bf16x8 r;
  asm volatile("global_load_dwordx4 %0, %1, off" : "=&v"(r) : "v"(p));
  return r;
}
__device__ __forceinline__ void vmwait0() {
  asm volatile("s_waitcnt vmcnt(0)");
  __builtin_amdgcn_sched_barrier(0);  // rule #18
}

// ---------------- f32 -> bf16: x + all 4 weights in one dispatch ----------------
__global__ __launch_bounds__(256) void cvt_all(const float* __restrict__ x,
                                               const float* __restrict__ Wq,
                                               const float* __restrict__ Wk,
                                               const float* __restrict__ Wv,
                                               const float* __restrict__ Wp,
                                               u16* __restrict__ dst) {
  const int i = blockIdx.x * 256 + threadIdx.x;  // 1,474,560 float4 items exactly
  const float* s;
  if (i < 884736) {
    s = x + (size_t)i * 4;
  } else {
    const int j = i - 884736;
    if (j < 147456) s = Wq + (size_t)j * 4;
    else if (j < 294912) s = Wk + (size_t)(j - 147456) * 4;
    else if (j < 442368) s = Wv + (size_t)(j - 294912) * 4;
    else s = Wp + (size_t)(j - 442368) * 4;
  }
  const float4 v = *(const float4*)s;
  ushort4 o;
  o.x = f2bf(v.x); o.y = f2bf(v.y); o.z = f2bf(v.z); o.w = f2bf(v.w);
  ((ushort4*)dst)[i] = o;
}

// ---------------- g-scaled positional softmax, materialized ----------------
__global__ __launch_bounds__(256) void pos_soft(const float* __restrict__ Wpos,
                                                const float* __restrict__ bpos,
                                                const float* __restrict__ gating,
                                                u16* __restrict__ posg) {
  const int w = threadIdx.x >> 6, lane = threadIdx.x & 63;
  const int row = blockIdx.x * 4 + w;            // 0..9215  (h*576+n)
  const int h = row / 576, n = row - h * 576;
  const float w0 = Wpos[h * 3 + 0], w1 = Wpos[h * 3 + 1], w2 = Wpos[h * 3 + 2], bp = bpos[h];
  const float g = 1.f / (1.f + __expf(-gating[h]));
  const int qr = n / 24, qc = n - qr * 24;
  float vals[9], evals[9];
  float mx = -1e30f;
#pragma unroll
  for (int i = 0; i < 9; ++i) {
    const int m = i * 64 + lane;
    const int kr = m / 24, kc = m - kr * 24;
    const float dx = (float)(kc - qc), dy = (float)(kr - qr);
    const float p = w0 * dx + w1 * dy + w2 * (dx * dx + dy * dy) + bp;
    vals[i] = p;
    mx = fmaxf(mx, p);
  }
#pragma unroll
  for (int off = 1; off < 64; off <<= 1) mx = fmaxf(mx, __shfl_xor(mx, off, 64));
  float s = 0.f;
#pragma unroll
  for (int i = 0; i < 9; ++i) { evals[i] = __expf(vals[i] - mx); s += evals[i]; }
#pragma unroll
  for (int off = 1; off < 64; off <<= 1) s += __shfl_xor(s, off, 64);
  const float gi = g / s;
  u16* out = posg + (size_t)row * 576;
#pragma unroll
  for (int i = 0; i < 9; ++i) out[i * 64 + lane] = f2bf(evals[i] * gi);
}

// ---------------- unified QKV projection (C = W @ x^T per mode), K = 768 ----------------
// R8 known-good: 128x128 tile, BK=32, 2-phase dbuf, 216x3 blocks.
__global__ __launch_bounds__(256, 2) void gemm_qkv(
    const u16* __restrict__ wq, const u16* __restrict__ wk, const u16* __restrict__ wv,
    const u16* __restrict__ xb, u16* __restrict__ Qo, u16* __restrict__ Ko,
    u16* __restrict__ Vo) {
  __shared__ u16 sA[2][128 * 32];
  __shared__ u16 sB[2][128 * 32];

  const int y = blockIdx.y;
  const u16* A = y == 0 ? wq : y == 1 ? wk : wv;

  const int mt = blockIdx.x / 36, nt = blockIdx.x % 36;
  const int mbase = mt * 128, nbase = nt * 128;
  const int tid = threadIdx.x;
  const int w = tid >> 6, lane = tid & 63;
  const int wr = w >> 1, wc = w & 1;
  const int lg = lane >> 4, lc = lane & 15;
  const int lrow = lane >> 2;
  const int lcol = (lane & 3) * 8;

  const u16* srcA0 = A + (size_t)(mbase + w * 16 + lrow) * 768 + lcol;
  const u16* srcA1 = srcA0 + (size_t)64 * 768;
  const u16* srcB0 = xb + (size_t)(nbase + w * 16 + lrow) * 768 + lcol;
  const u16* srcB1 = srcB0 + (size_t)64 * 768;
  const int dof = w * 512;

  const f32x4 vzero = {0.f, 0.f, 0.f, 0.f};
  f32x4 acc[4][4];
#pragma unroll
  for (int i = 0; i < 4; ++i)
#pragma unroll
    for (int j = 0; j < 4; ++j) acc[i][j] = vzero;

  gl_lds16(srcA0, sA[0] + dof);
  gl_lds16(srcA1, sA[0] + 2048 + dof);
  gl_lds16(srcB0, sB[0] + dof);
  gl_lds16(srcB1, sB[0] + 2048 + dof);
  __syncthreads();

  int buf = 0;
  for (int kt = 0; kt < 24; ++kt) {
    const int nb = buf ^ 1;
    if (kt < 23) {
      const int kb = (kt + 1) * 32;
      gl_lds16(srcA0 + kb, sA[nb] + dof);
      gl_lds16(srcA1 + kb, sA[nb] + 2048 + dof);
      gl_lds16(srcB0 + kb, sB[nb] + dof);
      gl_lds16(srcB1 + kb, sB[nb] + 2048 + dof);
    }
    bf16x8 av[4], bv[4];
#pragma unroll
    for (int i = 0; i < 4; ++i)
      av[i] = *(const bf16x8*)&sA[buf][(wr * 64 + i * 16 + lc) * 32 + lg * 8];
#pragma unroll
    for (int jn = 0; jn < 4; ++jn)
      bv[jn] = *(const bf16x8*)&sB[buf][(wc * 64 + jn * 16 + lc) * 32 + lg * 8];
#pragma unroll
    for (int i = 0; i < 4; ++i)
#pragma unroll
      for (int jn = 0; jn < 4; ++jn)
        acc[i][jn] = __builtin_amdgcn_mfma_f32_16x16x32_bf16(av[i], bv[jn], acc[i][jn], 0, 0, 0);
    __syncthreads();
    buf = nb;
  }

  if (y < 2) {
    const float qsc = (y == 0) ? 0.14433756729740643f : 1.0f;  // 48^-0.5 folded into Q
    u16* ob = (y == 0) ? Qo : Ko;
    const float4 zf4 = {0.f, 0.f, 0.f, 0.f};
#pragma unroll
    for (int i = 0; i < 4; ++i) {
      const int c0 = mbase + wr * 64 + i * 16 + lg * 4;
      const int hh = c0 / 48;
      const int d0 = c0 - hh * 48;
      const bool padw = (d0 == 44);
#pragma unroll
      for (int jn = 0; jn < 4; ++jn) {
        const int bn = nbase + wc * 64 + jn * 16 + lc;
        const int bb = bn / 576;
        const int nn = bn - bb * 576;
        u16* rowp = &ob[(((size_t)bb * 16 + hh) * 576 + nn) * 64 + d0];
        ushort4 o;
        o.x = f2bf(acc[i][jn][0] * qsc); o.y = f2bf(acc[i][jn][1] * qsc);
        o.z = f2bf(acc[i][jn][2] * qsc); o.w = f2bf(acc[i][jn][3] * qsc);
        *(ushort4*)rowp = o;
        if (padw) {
          *(float4*)(rowp + 4) = zf4;
          *(float4*)(rowp + 12) = zf4;
        }
      }
    }
  } else {
#pragma unroll
    for (int i = 0; i < 4; ++i) {
      const int c0 = mbase + wr * 64 + i * 16 + lg * 4;
      const int hh = c0 / 48;
      const int d0 = c0 - hh * 48;
#pragma unroll
      for (int jn = 0; jn < 4; ++jn) {
        const int bn = nbase + wc * 64 + jn * 16 + lc;
        const int bb = bn / 576;
        const int nn = bn - bb * 576;
#pragma unroll
        for (int j = 0; j < 4; ++j)
          Vo[(((size_t)bb * 16 + hh) * 48 + d0 + j) * 576 + nn] = f2bf(acc[i][jn][j]);
      }
    }
  }
}

// ---------------- pos-attention GEMM body: O2[b,h,q,d] = sum_m V[b,m,d]*posg[h,q,m] ----------------
// smem use: sA 2x4096 u16 (16KB) + sB 2x2048 u16 (8KB) = 24576 B.
__device__ __forceinline__ void pos_gemm_body(int id, const u16* __restrict__ VT,
                                              const u16* __restrict__ posg,
                                              u16* __restrict__ O, char* smem) {
  u16* sAm = (u16*)smem;             // [2][4096]
  u16* sBm = (u16*)(smem + 16384);   // [2][2048]

  const int xcd = id & 7;
  const int local = id >> 3;        // 0..53
  const int h = xcd * 2 + local / 27;
  const int r = local % 27;
  const int mt = r / 9, nt = r % 9;

  const int mbase = mt * 128, nbase = nt * 64;
  const int tid = threadIdx.x;
  const int w = tid >> 6, lane = tid & 63;
  const int wr = w >> 1, wc = w & 1;
  const int lg = lane >> 4, lc = lane & 15;
  const int lrow = lane >> 2;
  const int lcol = (lane & 3) * 8;

  const int mA0 = mbase + w * 16 + lrow, mA1 = mA0 + 64;
  const u16* srcA0 = VT + ((size_t)((mA0 / 48) * 16 + h) * 48 + (mA0 % 48)) * 576 + lcol;
  const u16* srcA1 = VT + ((size_t)((mA1 / 48) * 16 + h) * 48 + (mA1 % 48)) * 576 + lcol;
  const u16* srcB0 = posg + (size_t)(h * 576 + nbase + w * 16 + lrow) * 576 + lcol;
  const int dof = w * 512;

  const f32x4 vzero = {0.f, 0.f, 0.f, 0.f};
  f32x4 acc[4][2];
#pragma unroll
  for (int i = 0; i < 4; ++i)
#pragma unroll
    for (int j = 0; j < 2; ++j) acc[i][j] = vzero;

  gl_lds16(srcA0, sAm + dof);
  gl_lds16(srcA1, sAm + 2048 + dof);
  gl_lds16(srcB0, sBm + dof);
  __syncthreads();

  int buf = 0;
  for (int kt = 0; kt < 18; ++kt) {
    const int nb = buf ^ 1;
    if (kt < 17) {
      const int kb = (kt + 1) * 32;
      gl_lds16(srcA0 + kb, sAm + nb * 4096 + dof);
      gl_lds16(srcA1 + kb, sAm + nb * 4096 + 2048 + dof);
      gl_lds16(srcB0 + kb, sBm + nb * 2048 + dof);
    }
    bf16x8 av[4], bv[2];
#pragma unroll
    for (int i = 0; i < 4; ++i)
      av[i] = *(const bf16x8*)&sAm[buf * 4096 + (wr * 64 + i * 16 + lc) * 32 + lg * 8];
#pragma unroll
    for (int jn = 0; jn < 2; ++jn)
      bv[jn] = *(const bf16x8*)&sBm[buf * 2048 + (wc * 32 + jn * 16 + lc) * 32 + lg * 8];
#pragma unroll
    for (int i = 0; i < 4; ++i)
#pragma unroll
      for (int jn = 0; jn < 2; ++jn)
        acc[i][jn] = __builtin_amdgcn_mfma_f32_16x16x32_bf16(av[i], bv[jn], acc[i][jn], 0, 0, 0);
    __syncthreads();
    buf = nb;
  }

#pragma unroll
  for (int i = 0; i < 4; ++i) {
    const int c0 = mbase + wr * 64 + i * 16 + lg * 4;
    const int bb = c0 / 48;
    const int d0 = c0 - bb * 48;
#pragma unroll
    for (int jn = 0; jn < 2; ++jn) {
      const int q = nbase + wc * 32 + jn * 16 + lc;
      ushort4 o;
      o.x = f2bf(acc[i][jn][0]); o.y = f2bf(acc[i][jn][1]);
      o.z = f2bf(acc[i][jn][2]); o.w = f2bf(acc[i][jn][3]);
      *(ushort4*)&O[((size_t)(bb * 576 + q)) * 768 + h * 48 + d0] = o;
    }
  }
}

// ---------------- fused patch attention body ----------------
// RMW=false: plain store of (1-g)*O_p/l into O (pos part added later in proj).
// RMW=true : legacy read-modify-write (fallback path, pos pre-added in O).
// smem use: red[6][64][13] f32 = 19968 B.
template <bool RMW>
__device__ __forceinline__ void attn_body(int id, const u16* __restrict__ Q,
                                          const u16* __restrict__ K,
                                          const u16* __restrict__ VT,
                                          const float* __restrict__ gating,
                                          u16* __restrict__ O, char* smem) {
  float* red = (float*)smem;  // [6][64][13]
  const int b = id & 7;
  const int local = id >> 3;        // 0..95
  const int h = local / 6;
  const int qt = local % 6;
  const int tid = threadIdx.x;
  const int w = tid >> 6, lane = tid & 63;
  const int qh = w >> 1, ks = w & 1;
  const int lg = lane >> 4, lc = lane & 15;
  const int bh = b * 16 + h;

  const u16* Qh = Q + (size_t)bh * 576 * 64;
  const u16* Kh = K + (size_t)bh * 576 * 64;
  const u16* Vh = VT + (size_t)bh * 48 * 576;

  const bf16x8 zer = {0, 0, 0, 0, 0, 0, 0, 0};
  const int qbase = qt * 96 + qh * 48;
  bf16x8 aq[3][2];
#pragma unroll
  for (int qs = 0; qs < 3; ++qs) {
    aq[qs][0] = *(const bf16x8*)&Qh[(qbase + qs * 16 + lc) * 64 + lg * 8];
    aq[qs][1] = *(const bf16x8*)&Qh[(qbase + qs * 16 + lc) * 64 + 32 + lg * 8];
  }

  const int kbase = ks * 288;

  bf16x8 kb[2][2][2];
  bf16x8 vb[2][3];
#pragma unroll
  for (int t = 0; t < 2; ++t) {
    kb[0][t][0] = gload16(&Kh[(kbase + t * 16 + lc) * 64 + lg * 8]);
    kb[0][t][1] = gload16(&Kh[(kbase + t * 16 + lc) * 64 + 32 + lg * 8]);
  }
  vmwait0();

  const f32x4 vzero = {0.f, 0.f, 0.f, 0.f};
  f32x4 accP[3][3];
#pragma unroll
  for (int qs = 0; qs < 3; ++qs)
#pragma unroll
    for (int dt = 0; dt < 3; ++dt) accP[qs][dt] = vzero;
  float lsum[3] = {0.f, 0.f, 0.f};
  bf16x8 pfrag[3] = {zer, zer, zer};

  const int bpA = (((lg & 1) * 32) + lc) * 4;
  const int bpB = bpA + 64;
  const bool hiK = lg >= 2;

#pragma unroll
  for (int kc = 0; kc < 9; ++kc) {
    const int cur = kc & 1;
    const int k0 = kbase + kc * 32;
    if (kc < 8) {
      const int k1 = k0 + 32;
#pragma unroll
      for (int t = 0; t < 2; ++t) {
        kb[cur ^ 1][t][0] = gload16(&Kh[(k1 + t * 16 + lc) * 64 + lg * 8]);
        kb[cur ^ 1][t][1] = gload16(&Kh[(k1 + t * 16 + lc) * 64 + 32 + lg * 8]);
      }
    }
    vb[cur][0] = gload16(&Vh[lc * 576 + k0 + lg * 8]);
    vb[cur][1] = gload16(&Vh[(16 + lc) * 576 + k0 + lg * 8]);
    vb[cur][2] = gload16(&Vh[(32 + lc) * 576 + k0 + lg * 8]);

    f32x4 s0[3], s1[3];
    __builtin_amdgcn_s_setprio(1);  // T5: favor MFMA wave vs co-resident loaders
#pragma unroll
    for (int qs = 0; qs < 3; ++qs) {
      f32x4 a = vzero, c = vzero;
      a = __builtin_amdgcn_mfma_f32_16x16x32_bf16(kb[cur][0][0], aq[qs][0], a, 0, 0, 0);
      a = __builtin_amdgcn_mfma_f32_16x16x32_bf16(kb[cur][0][1], aq[qs][1], a, 0, 0, 0);
      c = __builtin_amdgcn_mfma_f32_16x16x32_bf16(kb[cur][1][0], aq[qs][0], c, 0, 0, 0);
      c = __builtin_amdgcn_mfma_f32_16x16x32_bf16(kb[cur][1][1], aq[qs][1], c, 0, 0, 0);
      s0[qs] = a; s1[qs] = c;
    }
    if (kc > 0) {
#pragma unroll
      for (int qs = 0; qs < 3; ++qs) {
        accP[qs][0] = __builtin_amdgcn_mfma_f32_16x16x32_bf16(vb[cur ^ 1][0], pfrag[qs], accP[qs][0], 0, 0, 0);
        accP[qs][1] = __builtin_amdgcn_mfma_f32_16x16x32_bf16(vb[cur ^ 1][1], pfrag[qs], accP[qs][1], 0, 0, 0);
        accP[qs][2] = __builtin_amdgcn_mfma_f32_16x16x32_bf16(vb[cur ^ 1][2], pfrag[qs], accP[qs][2], 0, 0, 0);
      }
    }
    __builtin_amdgcn_s_setprio(0);

#pragma unroll
    for (int qs = 0; qs < 3; ++qs) {
      const float p00 = __expf(s0[qs][0]), p01 = __expf(s0[qs][1]);
      const float p02 = __expf(s0[qs][2]), p03 = __expf(s0[qs][3]);
      const float p10 = __expf(s1[qs][0]), p11 = __expf(s1[qs][1]);
      const float p12 = __expf(s1[qs][2]), p13 = __expf(s1[qs][3]);
      lsum[qs] += ((p00 + p01) + (p02 + p03)) + ((p10 + p11) + (p12 + p13));

      uint32_t c0, c1, d0, d1;
      asm("v_cvt_pk_bf16_f32 %0, %1, %2" : "=v"(c0) : "v"(p00), "v"(p01));
      asm("v_cvt_pk_bf16_f32 %0, %1, %2" : "=v"(c1) : "v"(p02), "v"(p03));
      asm("v_cvt_pk_bf16_f32 %0, %1, %2" : "=v"(d0) : "v"(p10), "v"(p11));
      asm("v_cvt_pk_bf16_f32 %0, %1, %2" : "=v"(d1) : "v"(p12), "v"(p13));

      const int a_c0 = __builtin_amdgcn_ds_bpermute(bpA, (int)c0);
      const int a_c1 = __builtin_amdgcn_ds_bpermute(bpA, (int)c1);
      const int a_d0 = __builtin_amdgcn_ds_bpermute(bpA, (int)d0);
      const int a_d1 = __builtin_amdgcn_ds_bpermute(bpA, (int)d1);
      const int b_c0 = __builtin_amdgcn_ds_bpermute(bpB, (int)c0);
      const int b_c1 = __builtin_amdgcn_ds_bpermute(bpB, (int)c1);
      const int b_d0 = __builtin_amdgcn_ds_bpermute(bpB, (int)d0);
      const int b_d1 = __builtin_amdgcn_ds_bpermute(bpB, (int)d1);
      union { uint32_t u[4]; bf16x8 v; } pf;
      pf.u[0] = hiK ? a_d0 : a_c0;
      pf.u[1] = hiK ? a_d1 : a_c1;
      pf.u[2] = hiK ? b_d0 : b_c0;
      pf.u[3] = hiK ? b_d1 : b_c1;
      pfrag[qs] = pf.v;
    }
    vmwait0();
  }
#pragma unroll
  for (int qs = 0; qs < 3; ++qs) {
    accP[qs][0] = __builtin_amdgcn_mfma_f32_16x16x32_bf16(vb[0][0], pfrag[qs], accP[qs][0], 0, 0, 0);
    accP[qs][1] = __builtin_amdgcn_mfma_f32_16x16x32_bf16(vb[0][1], pfrag[qs], accP[qs][1], 0, 0, 0);
    accP[qs][2] = __builtin_amdgcn_mfma_f32_16x16x32_bf16(vb[0][2], pfrag[qs], accP[qs][2], 0, 0, 0);
  }

  float ls[3];
#pragma unroll
  for (int qs = 0; qs < 3; ++qs) {
    float t = lsum[qs];
    t += __shfl_xor(t, 16, 64);
    t += __shfl_xor(t, 32, 64);
    ls[qs] = t;
  }

  if (ks == 1) {
#pragma unroll
    for (int qs = 0; qs < 3; ++qs) {
#pragma unroll
      for (int j = 0; j < 4; ++j) {
        red[(qh * 3 + qs) * 832 + lane * 13 + 0 + j] = accP[qs][0][j];
        red[(qh * 3 + qs) * 832 + lane * 13 + 4 + j] = accP[qs][1][j];
        red[(qh * 3 + qs) * 832 + lane * 13 + 8 + j] = accP[qs][2][j];
      }
      red[(qh * 3 + qs) * 832 + lane * 13 + 12] = ls[qs];
    }
  }
  __syncthreads();
  if (ks == 0) {
    const float g = 1.f / (1.f + __expf(-gating[h]));
#pragma unroll
    for (int qs = 0; qs < 3; ++qs) {
      const float* rr = &red[(qh * 3 + qs) * 832 + lane * 13];
      const float linv = (1.f - g) / (ls[qs] + rr[12]);
      const int row = b * 576 + qbase + qs * 16 + lc;
#pragma unroll
      for (int dt = 0; dt < 3; ++dt) {
        const f32x4 a = accP[qs][dt];
        const size_t idx = (size_t)row * 768 + h * 48 + dt * 16 + lg * 4;
        ushort4 o;
        if constexpr (RMW) {
          const ushort4 old4 = *(const ushort4*)&O[idx];
          o.x = f2bf((a[0] + rr[dt * 4 + 0]) * linv + bf2f(old4.x));
          o.y = f2bf((a[1] + rr[dt * 4 + 1]) * linv + bf2f(old4.y));
          o.z = f2bf((a[2] + rr[dt * 4 + 2]) * linv + bf2f(old4.z));
          o.w = f2bf((a[3] + rr[dt * 4 + 3]) * linv + bf2f(old4.w));
        } else {
          o.x = f2bf((a[0] + rr[dt * 4 + 0]) * linv);
          o.y = f2bf((a[1] + rr[dt * 4 + 1]) * linv);
          o.z = f2bf((a[2] + rr[dt * 4 + 2]) * linv);
          o.w = f2bf((a[3] + rr[dt * 4 + 3]) * linv);
        }
        *(ushort4*)&O[idx] = o;
      }
    }
  }
}

// Merged dispatch: blocks 0..767 = attn (writes O1), 768..1199 = pos_gemm (writes O2).
// Independent outputs -> no intra-dispatch ordering needed; pos blocks fill attn's tail.
__global__ __launch_bounds__(256, 2) void pos_attn(
    const u16* __restrict__ Q, const u16* __restrict__ K, const u16* __restrict__ VT,
    const u16* __restrict__ posg, const float* __restrict__ gating,
    u16* __restrict__ O1, u16* __restrict__ O2) {
  __shared__ __align__(16) char smem[24576];
  if (blockIdx.x < 768)
    attn_body<false>(blockIdx.x, Q, K, VT, gating, O1, smem);
  else
    pos_gemm_body(blockIdx.x - 768, VT, posg, O2, smem);
}

// Fallback standalone kernels (ws too small for O1): serial R13 path.
__global__ __launch_bounds__(256, 2) void pos_gemm_k(const u16* __restrict__ VT,
                                                     const u16* __restrict__ posg,
                                                     u16* __restrict__ O) {
  __shared__ __align__(16) char smem[24576];
  pos_gemm_body(blockIdx.x, VT, posg, O, smem);
}
__global__ __launch_bounds__(256, 2) void attn_rmw_k(
    const u16* __restrict__ Q, const u16* __restrict__ K, const u16* __restrict__ VT,
    const float* __restrict__ gating, u16* __restrict__ O) {
  __shared__ __align__(16) char smem[19968];
  attn_body<true>(blockIdx.x, Q, K, VT, gating, O, smem);
}

// ---------------- output projection: out = (B1 [+ B2]) @ Wproj^T + bias ----------------
// SUM=true: B operand = bf16(O1+O2), reg-staged (load both, f32-add, repack, ds_write).
template <bool SUM>
__global__ __launch_bounds__(256, 2) void gemm_proj(const u16* __restrict__ A,
                                                    const u16* __restrict__ B1,
                                                    const u16* __restrict__ B2,
                                                    float* __restrict__ of,
                                                    const float* __restrict__ bias) {
  __shared__ u16 sA[2][128 * 32];
  __shared__ u16 sB[2][64 * 32];

  const int mt = blockIdx.x / 72, nt = blockIdx.x % 72;
  const int mbase = mt * 128, nbase = nt * 64;
  const int tid = threadIdx.x;
  const int w = tid >> 6, lane = tid & 63;
  const int wr = w >> 1, wc = w & 1;
  const int lg = lane >> 4, lc = lane & 15;
  const int lrow = lane >> 2;
  const int lcol = (lane & 3) * 8;

  const u16* srcA0 = A + (size_t)(mbase + w * 16 + lrow) * 768 + lcol;
  const u16* srcA1 = srcA0 + (size_t)64 * 768;
  const size_t boff = (size_t)(nbase + w * 16 + lrow) * 768 + lcol;
  const u16* srcB1 = B1 + boff;
  const u16* srcB2 = B2 + boff;
  const int dof = w * 512;
  const int wof = dof + lrow * 32 + (lane & 3) * 8;  // this lane's ds_write slot

  const f32x4 vzero = {0.f, 0.f, 0.f, 0.f};
  f32x4 acc[4][2];
#pragma unroll
  for (int i = 0; i < 4; ++i)
#pragma unroll
    for (int j = 0; j < 2; ++j) acc[i][j] = vzero;

  // prologue: B first (so its wait doesn't force gl_lds drain), then A via gl_lds
  if constexpr (SUM) {
    const bf16x8 rb1 = *(const bf16x8*)srcB1;
    const bf16x8 rb2 = *(const bf16x8*)srcB2;
    gl_lds16(srcA0, sA[0] + dof);
    gl_lds16(srcA1, sA[0] + 2048 + dof);
    bf16x8 rs;
#pragma unroll
    for (int e = 0; e < 8; ++e) rs[e] = (short)f2bf(bf2f((u16)rb1[e]) + bf2f((u16)rb2[e]));
    *(bf16x8*)&sB[0][wof] = rs;
  } else {
    gl_lds16(srcA0, sA[0] + dof);
    gl_lds16(srcA1, sA[0] + 2048 + dof);
    gl_lds16(srcB1, sB[0] + dof);
  }
  __syncthreads();

  int buf = 0;
  for (int kt = 0; kt < 24; ++kt) {
    const int nb = buf ^ 1;
    bf16x8 rb1, rb2;
    if (kt < 23) {
      const int kb = (kt + 1) * 32;
      if constexpr (SUM) {
        rb1 = *(const bf16x8*)(srcB1 + kb);
        rb2 = *(const bf16x8*)(srcB2 + kb);
      }
      gl_lds16(srcA0 + kb, sA[nb] + dof);
      gl_lds16(srcA1 + kb, sA[nb] + 2048 + dof);
      if constexpr (!SUM) gl_lds16(srcB1 + kb, sB[nb] + dof);
    }
    bf16x8 av[4], bv[2];
#pragma unroll
    for (int i = 0; i < 4; ++i)
      av[i] = *(const bf16x8*)&sA[buf][(wr * 64 + i * 16 + lc) * 32 + lg * 8];
#pragma unroll
    for (int jn = 0; jn < 2; ++jn)
      bv[jn] = *(const bf16x8*)&sB[buf][(wc * 32 + jn * 16 + lc) * 32 + lg * 8];
#pragma unroll
    for (int i = 0; i < 4; ++i)
#pragma unroll
      for (int jn = 0; jn < 2; ++jn)
        acc[i][jn] = __builtin_amdgcn_mfma_f32_16x16x32_bf16(av[i], bv[jn], acc[i][jn], 0, 0, 0);
    if constexpr (SUM) {
      if (kt < 23) {
        bf16x8 rs;
#pragma unroll
        for (int e = 0; e < 8; ++e) rs[e] = (short)f2bf(bf2f((u16)rb1[e]) + bf2f((u16)rb2[e]));
        *(bf16x8*)&sB[nb][wof] = rs;
      }
    }
    __syncthreads();
    buf = nb;
  }

#pragma unroll
  for (int i = 0; i < 4; ++i) {
    const int c0 = mbase + wr * 64 + i * 16 + lg * 4;
    const float4 b4 = *(const float4*)&bias[c0];
#pragma unroll
    for (int jn = 0; jn < 2; ++jn) {
      const int bn = nbase + wc * 32 + jn * 16 + lc;
      float4 o;
      o.x = acc[i][jn][0] + b4.x; o.y = acc[i][jn][1] + b4.y;
      o.z = acc[i][jn][2] + b4.z; o.w = acc[i][jn][3] + b4.w;
      *(float4*)&of[(size_t)bn * 768 + c0] = o;
    }
  }
}

// ---------------- launch ----------------
extern "C" void kernel_launch(void* const* d_in, const int* in_sizes, int n_in,
                              void* d_out, int out_size, void* d_ws, size_t ws_size,
                              hipStream_t stream) {
  const float* x      = (const float*)d_in[0];
  const float* Wq     = (const float*)d_in[1];
  const float* Wk     = (const float*)d_in[2];
  const float* Wv     = (const float*)d_in[3];
  const float* Wp     = (const float*)d_in[4];
  const float* bproj  = (const float*)d_in[5];
  const float* Wpos   = (const float*)d_in[6];
  const float* bpos   = (const float*)d_in[7];
  const float* gating = (const float*)d_in[8];
  float* out = (float*)d_out;

  char* ws = (char*)d_ws;
  u16* xb   = (u16*)(ws + 0);
  u16* wqb  = (u16*)(ws + 7077888);
  u16* wkb  = (u16*)(ws + 8257536);
  u16* wvb  = (u16*)(ws + 9437184);
  u16* wpb  = (u16*)(ws + 10616832);
  u16* Qw   = (u16*)(ws + 11796480);
  u16* Kw   = (u16*)(ws + 21233664);
  u16* VTw  = (u16*)(ws + 30670848);
  u16* O2w  = (u16*)(ws + 37748736);
  u16* O1w  = (u16*)(ws + 44826624);   // merged path only
  u16* posg = (u16*)(ws + 0);          // overlays xb..wvb (dead after gemm_qkv)

  cvt_all<<<dim3(5760), dim3(256), 0, stream>>>(x, Wq, Wk, Wv, Wp, xb);
  gemm_qkv<<<dim3(216, 3), dim3(256), 0, stream>>>(wqb, wkb, wvb, xb, Qw, Kw, VTw);
  pos_soft<<<dim3(2304), dim3(256), 0, stream>>>(Wpos, bpos, gating, posg);

  if (ws_size >= (size_t)51904512) {
    // merged: attn (O1) || pos_gemm (O2); proj sums B = O1 + O2
    pos_attn<<<dim3(1200), dim3(256), 0, stream>>>(Qw, Kw, VTw, posg, gating, O1w, O2w);
    gemm_proj<true><<<dim3(432), dim3(256), 0, stream>>>(wpb, O1w, O2w, out, bproj);
  } else {
    // fallback: serial R13 path
    pos_gemm_k<<<dim3(432), dim3(256), 0, stream>>>(VTw, posg, O2w);
    attn_rmw_k<<<dim3(768), dim3(256), 0, stream>>>(Qw, Kw, VTw, gating, O2w);
    gemm_proj<false><<<dim3(432), dim3(256), 0, stream>>>(wpb, O2w, O2w, out, bproj);
  }
}

// Round 15
// 109.957 us; speedup vs baseline: 1.0288x; 1.0028x over previous
//
#include <hip/hip_runtime.h>
#include <hip/hip_bf16.h>
#include <cstdint>

// ConViT GPSA fused pipeline, bf16 MFMA throughout.
// ws layout: xb(7.08M) wqb/wkb/wvb/wpb(1.18M ea) Q(9.44M) K(9.44M) VT(7.08M) O2(7.08M) O1(7.08M)
// posg(10.6M) overlays [xb..wvb] after gemm_qkv consumes them.
// Merged pos+attn dispatch needs ws >= 51,904,512 B; guarded fallback = serial path.

typedef unsigned short u16;
typedef __attribute__((ext_vector_type(8))) short bf16x8;
typedef __attribute__((ext_vector_type(4))) float f32x4;

__device__ __forceinline__ u16 f2bf(float f) {
  union { float f; uint32_t u; } v; v.f = f;
  uint32_t r = v.u + 0x7FFFu + ((v.u >> 16) & 1u);  // RNE (no NaN in this workload)
  return (u16)(r >> 16);
}
__device__ __forceinline__ float bf2f(u16 u) {
  union { uint32_t u; float f; } v; v.u = ((uint32_t)u) << 16;
  return v.f;
}

__device__ __forceinline__ void gl_lds16(const u16* g, u16* l) {
  __builtin_amdgcn_global_load_lds(
      (const __attribute__((address_space(1))) void*)g,
      (__attribute__((address_space(3))) void*)l, 16, 0, 0);
}
__device__ __forceinline__ bf16x8 gload16(const u16* p) {
  bf16x8 r;
  asm volatile("global_load_dwordx4 %0, %1, off" : "=&v"(r) : "v"(p));
  return r;
}
__device__ __forceinline__ void vmwait0() {
  asm volatile("s_waitcnt vmcnt(0)");
  __builtin_amdgcn_sched_barrier(0);  // rule #18
}

// ---------------- f32 -> bf16: x + all 4 weights in one dispatch ----------------
__global__ __launch_bounds__(256) void cvt_all(const float* __restrict__ x,
                                               const float* __restrict__ Wq,
                                               const float* __restrict__ Wk,
                                               const float* __restrict__ Wv,
                                               const float* __restrict__ Wp,
                                               u16* __restrict__ dst) {
  const int i = blockIdx.x * 256 + threadIdx.x;  // 1,474,560 float4 items exactly
  const float* s;
  if (i < 884736) {
    s = x + (size_t)i * 4;
  } else {
    const int j = i - 884736;
    if (j < 147456) s = Wq + (size_t)j * 4;
    else if (j < 294912) s = Wk + (size_t)(j - 147456) * 4;
    else if (j < 442368) s = Wv + (size_t)(j - 294912) * 4;
    else s = Wp + (size_t)(j - 442368) * 4;
  }
  const float4 v = *(const float4*)s;
  ushort4 o;
  o.x = f2bf(v.x); o.y = f2bf(v.y); o.z = f2bf(v.z); o.w = f2bf(v.w);
  ((ushort4*)dst)[i] = o;
}

// ---------------- g-scaled positional softmax, materialized ----------------
__global__ __launch_bounds__(256) void pos_soft(const float* __restrict__ Wpos,
                                                const float* __restrict__ bpos,
                                                const float* __restrict__ gating,
                                                u16* __restrict__ posg) {
  const int w = threadIdx.x >> 6, lane = threadIdx.x & 63;
  const int row = blockIdx.x * 4 + w;            // 0..9215  (h*576+n)
  const int h = row / 576, n = row - h * 576;
  const float w0 = Wpos[h * 3 + 0], w1 = Wpos[h * 3 + 1], w2 = Wpos[h * 3 + 2], bp = bpos[h];
  const float g = 1.f / (1.f + __expf(-gating[h]));
  const int qr = n / 24, qc = n - qr * 24;
  float vals[9], evals[9];
  float mx = -1e30f;
#pragma unroll
  for (int i = 0; i < 9; ++i) {
    const int m = i * 64 + lane;
    const int kr = m / 24, kc = m - kr * 24;
    const float dx = (float)(kc - qc), dy = (float)(kr - qr);
    const float p = w0 * dx + w1 * dy + w2 * (dx * dx + dy * dy) + bp;
    vals[i] = p;
    mx = fmaxf(mx, p);
  }
#pragma unroll
  for (int off = 1; off < 64; off <<= 1) mx = fmaxf(mx, __shfl_xor(mx, off, 64));
  float s = 0.f;
#pragma unroll
  for (int i = 0; i < 9; ++i) { evals[i] = __expf(vals[i] - mx); s += evals[i]; }
#pragma unroll
  for (int off = 1; off < 64; off <<= 1) s += __shfl_xor(s, off, 64);
  const float gi = g / s;
  u16* out = posg + (size_t)row * 576;
#pragma unroll
  for (int i = 0; i < 9; ++i) out[i * 64 + lane] = f2bf(evals[i] * gi);
}

// ---------------- unified QKV projection (C = W @ x^T per mode), K = 768 ----------------
// T4 counted-vmcnt pipeline: triple-buffered LDS, stage 2 tiles ahead, per-iter
// {issue stage(kt+2) -> s_waitcnt vmcnt(8) -> s_barrier -> 16 MFMA -> s_barrier}.
// Loads stay in flight ACROSS barriers (no vmcnt(0) drain until the 2-iter tail).
__global__ __launch_bounds__(256, 2) void gemm_qkv(
    const u16* __restrict__ wq, const u16* __restrict__ wk, const u16* __restrict__ wv,
    const u16* __restrict__ xb, u16* __restrict__ Qo, u16* __restrict__ Ko,
    u16* __restrict__ Vo) {
  __shared__ u16 sA[3][128 * 32];  // 3-deep ring, linear (global_load_lds dest)
  __shared__ u16 sB[3][128 * 32];

  const int y = blockIdx.y;
  const u16* A = y == 0 ? wq : y == 1 ? wk : wv;

  const int mt = blockIdx.x / 36, nt = blockIdx.x % 36;
  const int mbase = mt * 128, nbase = nt * 128;
  const int tid = threadIdx.x;
  const int w = tid >> 6, lane = tid & 63;
  const int wr = w >> 1, wc = w & 1;
  const int lg = lane >> 4, lc = lane & 15;
  const int lrow = lane >> 2;
  const int lcol = (lane & 3) * 8;

  const u16* srcA0 = A + (size_t)(mbase + w * 16 + lrow) * 768 + lcol;
  const u16* srcA1 = srcA0 + (size_t)64 * 768;
  const u16* srcB0 = xb + (size_t)(nbase + w * 16 + lrow) * 768 + lcol;
  const u16* srcB1 = srcB0 + (size_t)64 * 768;
  const int dof = w * 512;

  const f32x4 vzero = {0.f, 0.f, 0.f, 0.f};
  f32x4 acc[4][4];
#pragma unroll
  for (int i = 0; i < 4; ++i)
#pragma unroll
    for (int j = 0; j < 4; ++j) acc[i][j] = vzero;

  auto stage = [&](int kt, int slot) {
    const int kb = kt * 32;
    gl_lds16(srcA0 + kb, sA[slot] + dof);
    gl_lds16(srcA1 + kb, sA[slot] + 2048 + dof);
    gl_lds16(srcB0 + kb, sB[slot] + dof);
    gl_lds16(srcB1 + kb, sB[slot] + 2048 + dof);
  };
  auto compute = [&](int slot) {
    bf16x8 av[4], bv[4];
#pragma unroll
    for (int i = 0; i < 4; ++i)
      av[i] = *(const bf16x8*)&sA[slot][(wr * 64 + i * 16 + lc) * 32 + lg * 8];
#pragma unroll
    for (int jn = 0; jn < 4; ++jn)
      bv[jn] = *(const bf16x8*)&sB[slot][(wc * 64 + jn * 16 + lc) * 32 + lg * 8];
#pragma unroll
    for (int i = 0; i < 4; ++i)
#pragma unroll
      for (int jn = 0; jn < 4; ++jn)
        acc[i][jn] = __builtin_amdgcn_mfma_f32_16x16x32_bf16(av[i], bv[jn], acc[i][jn], 0, 0, 0);
  };

  // prologue: tiles 0,1 in flight
  stage(0, 0);
  stage(1, 1);

  for (int kt = 0; kt < 22; ++kt) {
    stage(kt + 2, (kt + 2) % 3);                       // keeps 2 tiles in flight
    asm volatile("s_waitcnt vmcnt(8)" ::: "memory");    // tile kt landed (8 = 2x4 newer)
    __builtin_amdgcn_sched_barrier(0);
    __builtin_amdgcn_s_barrier();                       // all waves' tile-kt loads landed
    compute(kt % 3);
    __builtin_amdgcn_s_barrier();                       // all waves done with slot kt%3
  }
  // tail: kt=22 (only tile 23's 4 loads newer), kt=23 (drain)
  asm volatile("s_waitcnt vmcnt(4)" ::: "memory");
  __builtin_amdgcn_sched_barrier(0);
  __builtin_amdgcn_s_barrier();
  compute(22 % 3);
  __builtin_amdgcn_s_barrier();
  asm volatile("s_waitcnt vmcnt(0)" ::: "memory");
  __builtin_amdgcn_sched_barrier(0);
  __builtin_amdgcn_s_barrier();
  compute(23 % 3);

  if (y < 2) {
    const float qsc = (y == 0) ? 0.14433756729740643f : 1.0f;  // 48^-0.5 folded into Q
    u16* ob = (y == 0) ? Qo : Ko;
    const float4 zf4 = {0.f, 0.f, 0.f, 0.f};
#pragma unroll
    for (int i = 0; i < 4; ++i) {
      const int c0 = mbase + wr * 64 + i * 16 + lg * 4;
      const int hh = c0 / 48;
      const int d0 = c0 - hh * 48;
      const bool padw = (d0 == 44);
#pragma unroll
      for (int jn = 0; jn < 4; ++jn) {
        const int bn = nbase + wc * 64 + jn * 16 + lc;
        const int bb = bn / 576;
        const int nn = bn - bb * 576;
        u16* rowp = &ob[(((size_t)bb * 16 + hh) * 576 + nn) * 64 + d0];
        ushort4 o;
        o.x = f2bf(acc[i][jn][0] * qsc); o.y = f2bf(acc[i][jn][1] * qsc);
        o.z = f2bf(acc[i][jn][2] * qsc); o.w = f2bf(acc[i][jn][3] * qsc);
        *(ushort4*)rowp = o;
        if (padw) {
          *(float4*)(rowp + 4) = zf4;
          *(float4*)(rowp + 12) = zf4;
        }
      }
    }
  } else {
#pragma unroll
    for (int i = 0; i < 4; ++i) {
      const int c0 = mbase + wr * 64 + i * 16 + lg * 4;
      const int hh = c0 / 48;
      const int d0 = c0 - hh * 48;
#pragma unroll
      for (int jn = 0; jn < 4; ++jn) {
        const int bn = nbase + wc * 64 + jn * 16 + lc;
        const int bb = bn / 576;
        const int nn = bn - bb * 576;
#pragma unroll
        for (int j = 0; j < 4; ++j)
          Vo[(((size_t)bb * 16 + hh) * 48 + d0 + j) * 576 + nn] = f2bf(acc[i][jn][j]);
      }
    }
  }
}

// ---------------- pos-attention GEMM body: O2[b,h,q,d] = sum_m V[b,m,d]*posg[h,q,m] ----------------
// smem use: sA 2x4096 u16 (16KB) + sB 2x2048 u16 (8KB) = 24576 B.
__device__ __forceinline__ void pos_gemm_body(int id, const u16* __restrict__ VT,
                                              const u16* __restrict__ posg,
                                              u16* __restrict__ O, char* smem) {
  u16* sAm = (u16*)smem;             // [2][4096]
  u16* sBm = (u16*)(smem + 16384);   // [2][2048]

  const int xcd = id & 7;
  const int local = id >> 3;        // 0..53
  const int h = xcd * 2 + local / 27;
  const int r = local % 27;
  const int mt = r / 9, nt = r % 9;

  const int mbase = mt * 128, nbase = nt * 64;
  const int tid = threadIdx.x;
  const int w = tid >> 6, lane = tid & 63;
  const int wr = w >> 1, wc = w & 1;
  const int lg = lane >> 4, lc = lane & 15;
  const int lrow = lane >> 2;
  const int lcol = (lane & 3) * 8;

  const int mA0 = mbase + w * 16 + lrow, mA1 = mA0 + 64;
  const u16* srcA0 = VT + ((size_t)((mA0 / 48) * 16 + h) * 48 + (mA0 % 48)) * 576 + lcol;
  const u16* srcA1 = VT + ((size_t)((mA1 / 48) * 16 + h) * 48 + (mA1 % 48)) * 576 + lcol;
  const u16* srcB0 = posg + (size_t)(h * 576 + nbase + w * 16 + lrow) * 576 + lcol;
  const int dof = w * 512;

  const f32x4 vzero = {0.f, 0.f, 0.f, 0.f};
  f32x4 acc[4][2];
#pragma unroll
  for (int i = 0; i < 4; ++i)
#pragma unroll
    for (int j = 0; j < 2; ++j) acc[i][j] = vzero;

  gl_lds16(srcA0, sAm + dof);
  gl_lds16(srcA1, sAm + 2048 + dof);
  gl_lds16(srcB0, sBm + dof);
  __syncthreads();

  int buf = 0;
  for (int kt = 0; kt < 18; ++kt) {
    const int nb = buf ^ 1;
    if (kt < 17) {
      const int kb = (kt + 1) * 32;
      gl_lds16(srcA0 + kb, sAm + nb * 4096 + dof);
      gl_lds16(srcA1 + kb, sAm + nb * 4096 + 2048 + dof);
      gl_lds16(srcB0 + kb, sBm + nb * 2048 + dof);
    }
    bf16x8 av[4], bv[2];
#pragma unroll
    for (int i = 0; i < 4; ++i)
      av[i] = *(const bf16x8*)&sAm[buf * 4096 + (wr * 64 + i * 16 + lc) * 32 + lg * 8];
#pragma unroll
    for (int jn = 0; jn < 2; ++jn)
      bv[jn] = *(const bf16x8*)&sBm[buf * 2048 + (wc * 32 + jn * 16 + lc) * 32 + lg * 8];
#pragma unroll
    for (int i = 0; i < 4; ++i)
#pragma unroll
      for (int jn = 0; jn < 2; ++jn)
        acc[i][jn] = __builtin_amdgcn_mfma_f32_16x16x32_bf16(av[i], bv[jn], acc[i][jn], 0, 0, 0);
    __syncthreads();
    buf = nb;
  }

#pragma unroll
  for (int i = 0; i < 4; ++i) {
    const int c0 = mbase + wr * 64 + i * 16 + lg * 4;
    const int bb = c0 / 48;
    const int d0 = c0 - bb * 48;
#pragma unroll
    for (int jn = 0; jn < 2; ++jn) {
      const int q = nbase + wc * 32 + jn * 16 + lc;
      ushort4 o;
      o.x = f2bf(acc[i][jn][0]); o.y = f2bf(acc[i][jn][1]);
      o.z = f2bf(acc[i][jn][2]); o.w = f2bf(acc[i][jn][3]);
      *(ushort4*)&O[((size_t)(bb * 576 + q)) * 768 + h * 48 + d0] = o;
    }
  }
}

// ---------------- fused patch attention body ----------------
// RMW=false: plain store of (1-g)*O_p/l into O (pos part added later in proj).
template <bool RMW>
__device__ __forceinline__ void attn_body(int id, const u16* __restrict__ Q,
                                          const u16* __restrict__ K,
                                          const u16* __restrict__ VT,
                                          const float* __restrict__ gating,
                                          u16* __restrict__ O, char* smem) {
  float* red = (float*)smem;  // [6][64][13]
  const int b = id & 7;
  const int local = id >> 3;        // 0..95
  const int h = local / 6;
  const int qt = local % 6;
  const int tid = threadIdx.x;
  const int w = tid >> 6, lane = tid & 63;
  const int qh = w >> 1, ks = w & 1;
  const int lg = lane >> 4, lc = lane & 15;
  const int bh = b * 16 + h;

  const u16* Qh = Q + (size_t)bh * 576 * 64;
  const u16* Kh = K + (size_t)bh * 576 * 64;
  const u16* Vh = VT + (size_t)bh * 48 * 576;

  const bf16x8 zer = {0, 0, 0, 0, 0, 0, 0, 0};
  const int qbase = qt * 96 + qh * 48;
  bf16x8 aq[3][2];
#pragma unroll
  for (int qs = 0; qs < 3; ++qs) {
    aq[qs][0] = *(const bf16x8*)&Qh[(qbase + qs * 16 + lc) * 64 + lg * 8];
    aq[qs][1] = *(const bf16x8*)&Qh[(qbase + qs * 16 + lc) * 64 + 32 + lg * 8];
  }

  const int kbase = ks * 288;

  bf16x8 kb[2][2][2];
  bf16x8 vb[2][3];
#pragma unroll
  for (int t = 0; t < 2; ++t) {
    kb[0][t][0] = gload16(&Kh[(kbase + t * 16 + lc) * 64 + lg * 8]);
    kb[0][t][1] = gload16(&Kh[(kbase + t * 16 + lc) * 64 + 32 + lg * 8]);
  }
  vmwait0();

  const f32x4 vzero = {0.f, 0.f, 0.f, 0.f};
  f32x4 accP[3][3];
#pragma unroll
  for (int qs = 0; qs < 3; ++qs)
#pragma unroll
    for (int dt = 0; dt < 3; ++dt) accP[qs][dt] = vzero;
  float lsum[3] = {0.f, 0.f, 0.f};
  bf16x8 pfrag[3] = {zer, zer, zer};

  const int bpA = (((lg & 1) * 32) + lc) * 4;
  const int bpB = bpA + 64;
  const bool hiK = lg >= 2;

#pragma unroll
  for (int kc = 0; kc < 9; ++kc) {
    const int cur = kc & 1;
    const int k0 = kbase + kc * 32;
    if (kc < 8) {
      const int k1 = k0 + 32;
#pragma unroll
      for (int t = 0; t < 2; ++t) {
        kb[cur ^ 1][t][0] = gload16(&Kh[(k1 + t * 16 + lc) * 64 + lg * 8]);
        kb[cur ^ 1][t][1] = gload16(&Kh[(k1 + t * 16 + lc) * 64 + 32 + lg * 8]);
      }
    }
    vb[cur][0] = gload16(&Vh[lc * 576 + k0 + lg * 8]);
    vb[cur][1] = gload16(&Vh[(16 + lc) * 576 + k0 + lg * 8]);
    vb[cur][2] = gload16(&Vh[(32 + lc) * 576 + k0 + lg * 8]);

    f32x4 s0[3], s1[3];
    __builtin_amdgcn_s_setprio(1);  // T5
#pragma unroll
    for (int qs = 0; qs < 3; ++qs) {
      f32x4 a = vzero, c = vzero;
      a = __builtin_amdgcn_mfma_f32_16x16x32_bf16(kb[cur][0][0], aq[qs][0], a, 0, 0, 0);
      a = __builtin_amdgcn_mfma_f32_16x16x32_bf16(kb[cur][0][1], aq[qs][1], a, 0, 0, 0);
      c = __builtin_amdgcn_mfma_f32_16x16x32_bf16(kb[cur][1][0], aq[qs][0], c, 0, 0, 0);
      c = __builtin_amdgcn_mfma_f32_16x16x32_bf16(kb[cur][1][1], aq[qs][1], c, 0, 0, 0);
      s0[qs] = a; s1[qs] = c;
    }
    if (kc > 0) {
#pragma unroll
      for (int qs = 0; qs < 3; ++qs) {
        accP[qs][0] = __builtin_amdgcn_mfma_f32_16x16x32_bf16(vb[cur ^ 1][0], pfrag[qs], accP[qs][0], 0, 0, 0);
        accP[qs][1] = __builtin_amdgcn_mfma_f32_16x16x32_bf16(vb[cur ^ 1][1], pfrag[qs], accP[qs][1], 0, 0, 0);
        accP[qs][2] = __builtin_amdgcn_mfma_f32_16x16x32_bf16(vb[cur ^ 1][2], pfrag[qs], accP[qs][2], 0, 0, 0);
      }
    }
    __builtin_amdgcn_s_setprio(0);

#pragma unroll
    for (int qs = 0; qs < 3; ++qs) {
      const float p00 = __expf(s0[qs][0]), p01 = __expf(s0[qs][1]);
      const float p02 = __expf(s0[qs][2]), p03 = __expf(s0[qs][3]);
      const float p10 = __expf(s1[qs][0]), p11 = __expf(s1[qs][1]);
      const float p12 = __expf(s1[qs][2]), p13 = __expf(s1[qs][3]);
      lsum[qs] += ((p00 + p01) + (p02 + p03)) + ((p10 + p11) + (p12 + p13));

      uint32_t c0, c1, d0, d1;
      asm("v_cvt_pk_bf16_f32 %0, %1, %2" : "=v"(c0) : "v"(p00), "v"(p01));
      asm("v_cvt_pk_bf16_f32 %0, %1, %2" : "=v"(c1) : "v"(p02), "v"(p03));
      asm("v_cvt_pk_bf16_f32 %0, %1, %2" : "=v"(d0) : "v"(p10), "v"(p11));
      asm("v_cvt_pk_bf16_f32 %0, %1, %2" : "=v"(d1) : "v"(p12), "v"(p13));

      const int a_c0 = __builtin_amdgcn_ds_bpermute(bpA, (int)c0);
      const int a_c1 = __builtin_amdgcn_ds_bpermute(bpA, (int)c1);
      const int a_d0 = __builtin_amdgcn_ds_bpermute(bpA, (int)d0);
      const int a_d1 = __builtin_amdgcn_ds_bpermute(bpA, (int)d1);
      const int b_c0 = __builtin_amdgcn_ds_bpermute(bpB, (int)c0);
      const int b_c1 = __builtin_amdgcn_ds_bpermute(bpB, (int)c1);
      const int b_d0 = __builtin_amdgcn_ds_bpermute(bpB, (int)d0);
      const int b_d1 = __builtin_amdgcn_ds_bpermute(bpB, (int)d1);
      union { uint32_t u[4]; bf16x8 v; } pf;
      pf.u[0] = hiK ? a_d0 : a_c0;
      pf.u[1] = hiK ? a_d1 : a_c1;
      pf.u[2] = hiK ? b_d0 : b_c0;
      pf.u[3] = hiK ? b_d1 : b_c1;
      pfrag[qs] = pf.v;
    }
    vmwait0();
  }
#pragma unroll
  for (int qs = 0; qs < 3; ++qs) {
    accP[qs][0] = __builtin_amdgcn_mfma_f32_16x16x32_bf16(vb[0][0], pfrag[qs], accP[qs][0], 0, 0, 0);
    accP[qs][1] = __builtin_amdgcn_mfma_f32_16x16x32_bf16(vb[0][1], pfrag[qs], accP[qs][1], 0, 0, 0);
    accP[qs][2] = __builtin_amdgcn_mfma_f32_16x16x32_bf16(vb[0][2], pfrag[qs], accP[qs][2], 0, 0, 0);
  }

  float ls[3];
#pragma unroll
  for (int qs = 0; qs < 3; ++qs) {
    float t = lsum[qs];
    t += __shfl_xor(t, 16, 64);
    t += __shfl_xor(t, 32, 64);
    ls[qs] = t;
  }

  if (ks == 1) {
#pragma unroll
    for (int qs = 0; qs < 3; ++qs) {
#pragma unroll
      for (int j = 0; j < 4; ++j) {
        red[(qh * 3 + qs) * 832 + lane * 13 + 0 + j] = accP[qs][0][j];
        red[(qh * 3 + qs) * 832 + lane * 13 + 4 + j] = accP[qs][1][j];
        red[(qh * 3 + qs) * 832 + lane * 13 + 8 + j] = accP[qs][2][j];
      }
      red[(qh * 3 + qs) * 832 + lane * 13 + 12] = ls[qs];
    }
  }
  __syncthreads();
  if (ks == 0) {
    const float g = 1.f / (1.f + __expf(-gating[h]));
#pragma unroll
    for (int qs = 0; qs < 3; ++qs) {
      const float* rr = &red[(qh * 3 + qs) * 832 + lane * 13];
      const float linv = (1.f - g) / (ls[qs] + rr[12]);
      const int row = b * 576 + qbase + qs * 16 + lc;
#pragma unroll
      for (int dt = 0; dt < 3; ++dt) {
        const f32x4 a = accP[qs][dt];
        const size_t idx = (size_t)row * 768 + h * 48 + dt * 16 + lg * 4;
        ushort4 o;
        if constexpr (RMW) {
          const ushort4 old4 = *(const ushort4*)&O[idx];
          o.x = f2bf((a[0] + rr[dt * 4 + 0]) * linv + bf2f(old4.x));
          o.y = f2bf((a[1] + rr[dt * 4 + 1]) * linv + bf2f(old4.y));
          o.z = f2bf((a[2] + rr[dt * 4 + 2]) * linv + bf2f(old4.z));
          o.w = f2bf((a[3] + rr[dt * 4 + 3]) * linv + bf2f(old4.w));
        } else {
          o.x = f2bf((a[0] + rr[dt * 4 + 0]) * linv);
          o.y = f2bf((a[1] + rr[dt * 4 + 1]) * linv);
          o.z = f2bf((a[2] + rr[dt * 4 + 2]) * linv);
          o.w = f2bf((a[3] + rr[dt * 4 + 3]) * linv);
        }
        *(ushort4*)&O[idx] = o;
      }
    }
  }
}

// Merged dispatch: blocks 0..767 = attn (writes O1), 768..1199 = pos_gemm (writes O2).
__global__ __launch_bounds__(256, 2) void pos_attn(
    const u16* __restrict__ Q, const u16* __restrict__ K, const u16* __restrict__ VT,
    const u16* __restrict__ posg, const float* __restrict__ gating,
    u16* __restrict__ O1, u16* __restrict__ O2) {
  __shared__ __align__(16) char smem[24576];
  if (blockIdx.x < 768)
    attn_body<false>(blockIdx.x, Q, K, VT, gating, O1, smem);
  else
    pos_gemm_body(blockIdx.x - 768, VT, posg, O2, smem);
}

// Fallback standalone kernels (ws too small for O1): serial path.
__global__ __launch_bounds__(256, 2) void pos_gemm_k(const u16* __restrict__ VT,
                                                     const u16* __restrict__ posg,
                                                     u16* __restrict__ O) {
  __shared__ __align__(16) char smem[24576];
  pos_gemm_body(blockIdx.x, VT, posg, O, smem);
}
__global__ __launch_bounds__(256, 2) void attn_rmw_k(
    const u16* __restrict__ Q, const u16* __restrict__ K, const u16* __restrict__ VT,
    const float* __restrict__ gating, u16* __restrict__ O) {
  __shared__ __align__(16) char smem[19968];
  attn_body<true>(blockIdx.x, Q, K, VT, gating, O, smem);
}

// ---------------- output projection: out = (B1 [+ B2]) @ Wproj^T + bias ----------------
template <bool SUM>
__global__ __launch_bounds__(256, 2) void gemm_proj(const u16* __restrict__ A,
                                                    const u16* __restrict__ B1,
                                                    const u16* __restrict__ B2,
                                                    float* __restrict__ of,
                                                    const float* __restrict__ bias) {
  __shared__ u16 sA[2][128 * 32];
  __shared__ u16 sB[2][64 * 32];

  const int mt = blockIdx.x / 72, nt = blockIdx.x % 72;
  const int mbase = mt * 128, nbase = nt * 64;
  const int tid = threadIdx.x;
  const int w = tid >> 6, lane = tid & 63;
  const int wr = w >> 1, wc = w & 1;
  const int lg = lane >> 4, lc = lane & 15;
  const int lrow = lane >> 2;
  const int lcol = (lane & 3) * 8;

  const u16* srcA0 = A + (size_t)(mbase + w * 16 + lrow) * 768 + lcol;
  const u16* srcA1 = srcA0 + (size_t)64 * 768;
  const size_t boff = (size_t)(nbase + w * 16 + lrow) * 768 + lcol;
  const u16* srcB1 = B1 + boff;
  const u16* srcB2 = B2 + boff;
  const int dof = w * 512;
  const int wof = dof + lrow * 32 + (lane & 3) * 8;

  const f32x4 vzero = {0.f, 0.f, 0.f, 0.f};
  f32x4 acc[4][2];
#pragma unroll
  for (int i = 0; i < 4; ++i)
#pragma unroll
    for (int j = 0; j < 2; ++j) acc[i][j] = vzero;

  if constexpr (SUM) {
    const bf16x8 rb1 = *(const bf16x8*)srcB1;
    const bf16x8 rb2 = *(const bf16x8*)srcB2;
    gl_lds16(srcA0, sA[0] + dof);
    gl_lds16(srcA1, sA[0] + 2048 + dof);
    bf16x8 rs;
#pragma unroll
    for (int e = 0; e < 8; ++e) rs[e] = (short)f2bf(bf2f((u16)rb1[e]) + bf2f((u16)rb2[e]));
    *(bf16x8*)&sB[0][wof] = rs;
  } else {
    gl_lds16(srcA0, sA[0] + dof);
    gl_lds16(srcA1, sA[0] + 2048 + dof);
    gl_lds16(srcB1, sB[0] + dof);
  }
  __syncthreads();

  int buf = 0;
  for (int kt = 0; kt < 24; ++kt) {
    const int nb = buf ^ 1;
    bf16x8 rb1, rb2;
    if (kt < 23) {
      const int kb = (kt + 1) * 32;
      if constexpr (SUM) {
        rb1 = *(const bf16x8*)(srcB1 + kb);
        rb2 = *(const bf16x8*)(srcB2 + kb);
      }
      gl_lds16(srcA0 + kb, sA[nb] + dof);
      gl_lds16(srcA1 + kb, sA[nb] + 2048 + dof);
      if constexpr (!SUM) gl_lds16(srcB1 + kb, sB[nb] + dof);
    }
    bf16x8 av[4], bv[2];
#pragma unroll
    for (int i = 0; i < 4; ++i)
      av[i] = *(const bf16x8*)&sA[buf][(wr * 64 + i * 16 + lc) * 32 + lg * 8];
#pragma unroll
    for (int jn = 0; jn < 2; ++jn)
      bv[jn] = *(const bf16x8*)&sB[buf][(wc * 32 + jn * 16 + lc) * 32 + lg * 8];
#pragma unroll
    for (int i = 0; i < 4; ++i)
#pragma unroll
      for (int jn = 0; jn < 2; ++jn)
        acc[i][jn] = __builtin_amdgcn_mfma_f32_16x16x32_bf16(av[i], bv[jn], acc[i][jn], 0, 0, 0);
    if constexpr (SUM) {
      if (kt < 23) {
        bf16x8 rs;
#pragma unroll
        for (int e = 0; e < 8; ++e) rs[e] = (short)f2bf(bf2f((u16)rb1[e]) + bf2f((u16)rb2[e]));
        *(bf16x8*)&sB[nb][wof] = rs;
      }
    }
    __syncthreads();
    buf = nb;
  }

#pragma unroll
  for (int i = 0; i < 4; ++i) {
    const int c0 = mbase + wr * 64 + i * 16 + lg * 4;
    const float4 b4 = *(const float4*)&bias[c0];
#pragma unroll
    for (int jn = 0; jn < 2; ++jn) {
      const int bn = nbase + wc * 32 + jn * 16 + lc;
      float4 o;
      o.x = acc[i][jn][0] + b4.x; o.y = acc[i][jn][1] + b4.y;
      o.z = acc[i][jn][2] + b4.z; o.w = acc[i][jn][3] + b4.w;
      *(float4*)&of[(size_t)bn * 768 + c0] = o;
    }
  }
}

// ---------------- launch ----------------
extern "C" void kernel_launch(void* const* d_in, const int* in_sizes, int n_in,
                              void* d_out, int out_size, void* d_ws, size_t ws_size,
                              hipStream_t stream) {
  const float* x      = (const float*)d_in[0];
  const float* Wq     = (const float*)d_in[1];
  const float* Wk     = (const float*)d_in[2];
  const float* Wv     = (const float*)d_in[3];
  const float* Wp     = (const float*)d_in[4];
  const float* bproj  = (const float*)d_in[5];
  const float* Wpos   = (const float*)d_in[6];
  const float* bpos   = (const float*)d_in[7];
  const float* gating = (const float*)d_in[8];
  float* out = (float*)d_out;

  char* ws = (char*)d_ws;
  u16* xb   = (u16*)(ws + 0);
  u16* wqb  = (u16*)(ws + 7077888);
  u16* wkb  = (u16*)(ws + 8257536);
  u16* wvb  = (u16*)(ws + 9437184);
  u16* wpb  = (u16*)(ws + 10616832);
  u16* Qw   = (u16*)(ws + 11796480);
  u16* Kw   = (u16*)(ws + 21233664);
  u16* VTw  = (u16*)(ws + 30670848);
  u16* O2w  = (u16*)(ws + 37748736);
  u16* O1w  = (u16*)(ws + 44826624);   // merged path only
  u16* posg = (u16*)(ws + 0);          // overlays xb..wvb (dead after gemm_qkv)

  cvt_all<<<dim3(5760), dim3(256), 0, stream>>>(x, Wq, Wk, Wv, Wp, xb);
  gemm_qkv<<<dim3(216, 3), dim3(256), 0, stream>>>(wqb, wkb, wvb, xb, Qw, Kw, VTw);
  pos_soft<<<dim3(2304), dim3(256), 0, stream>>>(Wpos, bpos, gating, posg);

  if (ws_size >= (size_t)51904512) {
    pos_attn<<<dim3(1200), dim3(256), 0, stream>>>(Qw, Kw, VTw, posg, gating, O1w, O2w);
    gemm_proj<true><<<dim3(432), dim3(256), 0, stream>>>(wpb, O1w, O2w, out, bproj);
  } else {
    pos_gemm_k<<<dim3(432), dim3(256), 0, stream>>>(VTw, posg, O2w);
    attn_rmw_k<<<dim3(768), dim3(256), 0, stream>>>(Qw, Kw, VTw, gating, O2w);
    gemm_proj<false><<<dim3(432), dim3(256), 0, stream>>>(wpb, O2w, O2w, out, bproj);
  }
}

// Round 17
// 101.397 us; speedup vs baseline: 1.1157x; 1.0844x over previous
//
#include <hip/hip_runtime.h>
#include <hip/hip_bf16.h>
#include <cstdint>

// ConViT GPSA fused pipeline, bf16 MFMA throughout.
// ws: xb(7.08M) wqb/wkb/wvb/wpb(1.18M ea) Q(9.44M) K(9.44M) VT(7.08M) O2(7.08M) O1(7.08M) [posg_hi 10.6M]
// posg placement tiered by ws_size: fresh @51,904,512 (merged cvt_pos) OR overlay @0 (pos_soft AFTER gemm_qkv).
// T2 LDS swizzle (all staged GEMMs): LDS(row,cb) holds global(row, cb^(((row&15)>>1)&3));
// pre-swizzled SOURCE column (linear gl_lds dest, rule #21) + swizzled read lgs.

typedef unsigned short u16;
typedef __attribute__((ext_vector_type(8))) short bf16x8;
typedef __attribute__((ext_vector_type(4))) float f32x4;

__device__ __forceinline__ u16 f2bf(float f) {
  union { float f; uint32_t u; } v; v.f = f;
  uint32_t r = v.u + 0x7FFFu + ((v.u >> 16) & 1u);  // RNE (no NaN in this workload)
  return (u16)(r >> 16);
}
__device__ __forceinline__ float bf2f(u16 u) {
  union { uint32_t u; float f; } v; v.u = ((uint32_t)u) << 16;
  return v.f;
}

__device__ __forceinline__ void gl_lds16(const u16* g, u16* l) {
  __builtin_amdgcn_global_load_lds(
      (const __attribute__((address_space(1))) void*)g,
      (__attribute__((address_space(3))) void*)l, 16, 0, 0);
}
__device__ __forceinline__ bf16x8 gload16(const u16* p) {
  bf16x8 r;
  asm volatile("global_load_dwordx4 %0, %1, off" : "=&v"(r) : "v"(p));
  return r;
}
__device__ __forceinline__ void vmwait0() {
  asm volatile("s_waitcnt vmcnt(0)");
  __builtin_amdgcn_sched_barrier(0);  // rule #18
}

// ---------------- pos softmax body ----------------
__device__ __forceinline__ void pos_body(int row, const float* __restrict__ Wpos,
                                         const float* __restrict__ bpos,
                                         const float* __restrict__ gating,
                                         u16* __restrict__ posg) {
  const int lane = threadIdx.x & 63;
  const int h = row / 576, n = row - h * 576;
  const float w0 = Wpos[h * 3 + 0], w1 = Wpos[h * 3 + 1], w2 = Wpos[h * 3 + 2], bp = bpos[h];
  const float g = 1.f / (1.f + __expf(-gating[h]));
  const int qr = n / 24, qc = n - qr * 24;
  float vals[9], evals[9];
  float mx = -1e30f;
#pragma unroll
  for (int i = 0; i < 9; ++i) {
    const int m = i * 64 + lane;
    const int kr = m / 24, kc = m - kr * 24;
    const float dx = (float)(kc - qc), dy = (float)(kr - qr);
    const float p = w0 * dx + w1 * dy + w2 * (dx * dx + dy * dy) + bp;
    vals[i] = p;
    mx = fmaxf(mx, p);
  }
#pragma unroll
  for (int off = 1; off < 64; off <<= 1) mx = fmaxf(mx, __shfl_xor(mx, off, 64));
  float s = 0.f;
#pragma unroll
  for (int i = 0; i < 9; ++i) { evals[i] = __expf(vals[i] - mx); s += evals[i]; }
#pragma unroll
  for (int off = 1; off < 64; off <<= 1) s += __shfl_xor(s, off, 64);
  const float gi = g / s;
  u16* out = posg + (size_t)row * 576;
#pragma unroll
  for (int i = 0; i < 9; ++i) out[i * 64 + lane] = f2bf(evals[i] * gi);
}

// merged: f32->bf16 cvt (blocks 0..5759) + pos softmax (5760..8063, only if grid > 5760).
__global__ __launch_bounds__(256) void cvt_pos(const float* __restrict__ x,
                                               const float* __restrict__ Wq,
                                               const float* __restrict__ Wk,
                                               const float* __restrict__ Wv,
                                               const float* __restrict__ Wp,
                                               u16* __restrict__ dst,
                                               const float* __restrict__ Wpos,
                                               const float* __restrict__ bpos,
                                               const float* __restrict__ gating,
                                               u16* __restrict__ posg) {
  if (blockIdx.x < 5760) {
    const int i = blockIdx.x * 256 + threadIdx.x;  // 1,474,560 float4 items exactly
    const float* s;
    if (i < 884736) {
      s = x + (size_t)i * 4;
    } else {
      const int j = i - 884736;
      if (j < 147456) s = Wq + (size_t)j * 4;
      else if (j < 294912) s = Wk + (size_t)(j - 147456) * 4;
      else if (j < 442368) s = Wv + (size_t)(j - 294912) * 4;
      else s = Wp + (size_t)(j - 442368) * 4;
    }
    const float4 v = *(const float4*)s;
    ushort4 o;
    o.x = f2bf(v.x); o.y = f2bf(v.y); o.z = f2bf(v.z); o.w = f2bf(v.w);
    ((ushort4*)dst)[i] = o;
  } else {
    pos_body((blockIdx.x - 5760) * 4 + (threadIdx.x >> 6), Wpos, bpos, gating, posg);
  }
}

__global__ __launch_bounds__(256) void pos_soft(const float* __restrict__ Wpos,
                                                const float* __restrict__ bpos,
                                                const float* __restrict__ gating,
                                                u16* __restrict__ posg) {
  pos_body(blockIdx.x * 4 + (threadIdx.x >> 6), Wpos, bpos, gating, posg);
}

// ---------------- unified QKV projection (C = W @ x^T per mode), K = 768 ----------------
// counted-vmcnt 3-ring + T2 swizzle (pre-swizzled source, swizzled read).
__global__ __launch_bounds__(256, 2) void gemm_qkv(
    const u16* __restrict__ wq, const u16* __restrict__ wk, const u16* __restrict__ wv,
    const u16* __restrict__ xb, u16* __restrict__ Qo, u16* __restrict__ Ko,
    u16* __restrict__ Vo) {
  __shared__ u16 sA[3][128 * 32];  // 3-deep ring, linear (global_load_lds dest)
  __shared__ u16 sB[3][128 * 32];

  const int y = blockIdx.y;
  const u16* A = y == 0 ? wq : y == 1 ? wk : wv;

  const int mt = blockIdx.x / 36, nt = blockIdx.x % 36;
  const int mbase = mt * 128, nbase = nt * 128;
  const int tid = threadIdx.x;
  const int w = tid >> 6, lane = tid & 63;
  const int wr = w >> 1, wc = w & 1;
  const int lg = lane >> 4, lc = lane & 15;
  const int lgs = lg ^ ((lc >> 1) & 3);      // swizzled read column-block
  const int lrow = lane >> 2;
  const int lcol = (((lane & 3) ^ ((lane >> 3) & 3))) * 8;  // pre-swizzled source col

  const u16* srcA0 = A + (size_t)(mbase + w * 16 + lrow) * 768 + lcol;
  const u16* srcA1 = srcA0 + (size_t)64 * 768;
  const u16* srcB0 = xb + (size_t)(nbase + w * 16 + lrow) * 768 + lcol;
  const u16* srcB1 = srcB0 + (size_t)64 * 768;
  const int dof = w * 512;

  const f32x4 vzero = {0.f, 0.f, 0.f, 0.f};
  f32x4 acc[4][4];
#pragma unroll
  for (int i = 0; i < 4; ++i)
#pragma unroll
    for (int j = 0; j < 4; ++j) acc[i][j] = vzero;

  auto stage = [&](int kt, int slot) {
    const int kb = kt * 32;
    gl_lds16(srcA0 + kb, sA[slot] + dof);
    gl_lds16(srcA1 + kb, sA[slot] + 2048 + dof);
    gl_lds16(srcB0 + kb, sB[slot] + dof);
    gl_lds16(srcB1 + kb, sB[slot] + 2048 + dof);
  };
  auto compute = [&](int slot) {
    bf16x8 av[4], bv[4];
#pragma unroll
    for (int i = 0; i < 4; ++i)
      av[i] = *(const bf16x8*)&sA[slot][(wr * 64 + i * 16 + lc) * 32 + lgs * 8];
#pragma unroll
    for (int jn = 0; jn < 4; ++jn)
      bv[jn] = *(const bf16x8*)&sB[slot][(wc * 64 + jn * 16 + lc) * 32 + lgs * 8];
#pragma unroll
    for (int i = 0; i < 4; ++i)
#pragma unroll
      for (int jn = 0; jn < 4; ++jn)
        acc[i][jn] = __builtin_amdgcn_mfma_f32_16x16x32_bf16(av[i], bv[jn], acc[i][jn], 0, 0, 0);
  };

  stage(0, 0);
  stage(1, 1);

  for (int kt = 0; kt < 22; ++kt) {
    stage(kt + 2, (kt + 2) % 3);
    asm volatile("s_waitcnt vmcnt(8)" ::: "memory");
    __builtin_amdgcn_sched_barrier(0);
    __builtin_amdgcn_s_barrier();
    compute(kt % 3);
    __builtin_amdgcn_s_barrier();
  }
  asm volatile("s_waitcnt vmcnt(4)" ::: "memory");
  __builtin_amdgcn_sched_barrier(0);
  __builtin_amdgcn_s_barrier();
  compute(22 % 3);
  __builtin_amdgcn_s_barrier();
  asm volatile("s_waitcnt vmcnt(0)" ::: "memory");
  __builtin_amdgcn_sched_barrier(0);
  __builtin_amdgcn_s_barrier();
  compute(23 % 3);

  if (y < 2) {
    const float qsc = (y == 0) ? 0.14433756729740643f : 1.0f;  // 48^-0.5 folded into Q
    u16* ob = (y == 0) ? Qo : Ko;
    const float4 zf4 = {0.f, 0.f, 0.f, 0.f};
#pragma unroll
    for (int i = 0; i < 4; ++i) {
      const int c0 = mbase + wr * 64 + i * 16 + lg * 4;
      const int hh = c0 / 48;
      const int d0 = c0 - hh * 48;
      const bool padw = (d0 == 44);
#pragma unroll
      for (int jn = 0; jn < 4; ++jn) {
        const int bn = nbase + wc * 64 + jn * 16 + lc;
        const int bb = bn / 576;
        const int nn = bn - bb * 576;
        u16* rowp = &ob[(((size_t)bb * 16 + hh) * 576 + nn) * 64 + d0];
        ushort4 o;
        o.x = f2bf(acc[i][jn][0] * qsc); o.y = f2bf(acc[i][jn][1] * qsc);
        o.z = f2bf(acc[i][jn][2] * qsc); o.w = f2bf(acc[i][jn][3] * qsc);
        *(ushort4*)rowp = o;
        if (padw) {
          *(float4*)(rowp + 4) = zf4;
          *(float4*)(rowp + 12) = zf4;
        }
      }
    }
  } else {
#pragma unroll
    for (int i = 0; i < 4; ++i) {
      const int c0 = mbase + wr * 64 + i * 16 + lg * 4;
      const int hh = c0 / 48;
      const int d0 = c0 - hh * 48;
#pragma unroll
      for (int jn = 0; jn < 4; ++jn) {
        const int bn = nbase + wc * 64 + jn * 16 + lc;
        const int bb = bn / 576;
        const int nn = bn - bb * 576;
#pragma unroll
        for (int j = 0; j < 4; ++j)
          Vo[(((size_t)bb * 16 + hh) * 48 + d0 + j) * 576 + nn] = f2bf(acc[i][jn][j]);
      }
    }
  }
}

// ---------------- pos-attention GEMM body (T2-swizzled) ----------------
__device__ __forceinline__ void pos_gemm_body(int id, const u16* __restrict__ VT,
                                              const u16* __restrict__ posg,
                                              u16* __restrict__ O, char* smem) {
  u16* sAm = (u16*)smem;             // [2][4096]
  u16* sBm = (u16*)(smem + 16384);   // [2][2048]

  const int xcd = id & 7;
  const int local = id >> 3;        // 0..53
  const int h = xcd * 2 + local / 27;
  const int r = local % 27;
  const int mt = r / 9, nt = r % 9;

  const int mbase = mt * 128, nbase = nt * 64;
  const int tid = threadIdx.x;
  const int w = tid >> 6, lane = tid & 63;
  const int wr = w >> 1, wc = w & 1;
  const int lg = lane >> 4, lc = lane & 15;
  const int lgs = lg ^ ((lc >> 1) & 3);
  const int lrow = lane >> 2;
  const int lcol = (((lane & 3) ^ ((lane >> 3) & 3))) * 8;

  const int mA0 = mbase + w * 16 + lrow, mA1 = mA0 + 64;
  const u16* srcA0 = VT + ((size_t)((mA0 / 48) * 16 + h) * 48 + (mA0 % 48)) * 576 + lcol;
  const u16* srcA1 = VT + ((size_t)((mA1 / 48) * 16 + h) * 48 + (mA1 % 48)) * 576 + lcol;
  const u16* srcB0 = posg + (size_t)(h * 576 + nbase + w * 16 + lrow) * 576 + lcol;
  const int dof = w * 512;

  const f32x4 vzero = {0.f, 0.f, 0.f, 0.f};
  f32x4 acc[4][2];
#pragma unroll
  for (int i = 0; i < 4; ++i)
#pragma unroll
    for (int j = 0; j < 2; ++j) acc[i][j] = vzero;

  gl_lds16(srcA0, sAm + dof);
  gl_lds16(srcA1, sAm + 2048 + dof);
  gl_lds16(srcB0, sBm + dof);
  __syncthreads();

  int buf = 0;
  for (int kt = 0; kt < 18; ++kt) {
    const int nb = buf ^ 1;
    if (kt < 17) {
      const int kb = (kt + 1) * 32;
      gl_lds16(srcA0 + kb, sAm + nb * 4096 + dof);
      gl_lds16(srcA1 + kb, sAm + nb * 4096 + 2048 + dof);
      gl_lds16(srcB0 + kb, sBm + nb * 2048 + dof);
    }
    bf16x8 av[4], bv[2];
#pragma unroll
    for (int i = 0; i < 4; ++i)
      av[i] = *(const bf16x8*)&sAm[buf * 4096 + (wr * 64 + i * 16 + lc) * 32 + lgs * 8];
#pragma unroll
    for (int jn = 0; jn < 2; ++jn)
      bv[jn] = *(const bf16x8*)&sBm[buf * 2048 + (wc * 32 + jn * 16 + lc) * 32 + lgs * 8];
#pragma unroll
    for (int i = 0; i < 4; ++i)
#pragma unroll
      for (int jn = 0; jn < 2; ++jn)
        acc[i][jn] = __builtin_amdgcn_mfma_f32_16x16x32_bf16(av[i], bv[jn], acc[i][jn], 0, 0, 0);
    __syncthreads();
    buf = nb;
  }

#pragma unroll
  for (int i = 0; i < 4; ++i) {
    const int c0 = mbase + wr * 64 + i * 16 + lg * 4;
    const int bb = c0 / 48;
    const int d0 = c0 - bb * 48;
#pragma unroll
    for (int jn = 0; jn < 2; ++jn) {
      const int q = nbase + wc * 32 + jn * 16 + lc;
      ushort4 o;
      o.x = f2bf(acc[i][jn][0]); o.y = f2bf(acc[i][jn][1]);
      o.z = f2bf(acc[i][jn][2]); o.w = f2bf(acc[i][jn][3]);
      *(ushort4*)&O[((size_t)(bb * 576 + q)) * 768 + h * 48 + d0] = o;
    }
  }
}

// ---------------- fused patch attention body ----------------
template <bool RMW>
__device__ __forceinline__ void attn_body(int id, const u16* __restrict__ Q,
                                          const u16* __restrict__ K,
                                          const u16* __restrict__ VT,
                                          const float* __restrict__ gating,
                                          u16* __restrict__ O, char* smem) {
  float* red = (float*)smem;  // [6][64][13]
  const int b = id & 7;
  const int local = id >> 3;        // 0..95
  const int h = local / 6;
  const int qt = local % 6;
  const int tid = threadIdx.x;
  const int w = tid >> 6, lane = tid & 63;
  const int qh = w >> 1, ks = w & 1;
  const int lg = lane >> 4, lc = lane & 15;
  const int bh = b * 16 + h;

  const u16* Qh = Q + (size_t)bh * 576 * 64;
  const u16* Kh = K + (size_t)bh * 576 * 64;
  const u16* Vh = VT + (size_t)bh * 48 * 576;

  const bf16x8 zer = {0, 0, 0, 0, 0, 0, 0, 0};
  const int qbase = qt * 96 + qh * 48;
  bf16x8 aq[3][2];
#pragma unroll
  for (int qs = 0; qs < 3; ++qs) {
    aq[qs][0] = *(const bf16x8*)&Qh[(qbase + qs * 16 + lc) * 64 + lg * 8];
    aq[qs][1] = *(const bf16x8*)&Qh[(qbase + qs * 16 + lc) * 64 + 32 + lg * 8];
  }

  const int kbase = ks * 288;

  bf16x8 kb[2][2][2];
  bf16x8 vb[2][3];
#pragma unroll
  for (int t = 0; t < 2; ++t) {
    kb[0][t][0] = gload16(&Kh[(kbase + t * 16 + lc) * 64 + lg * 8]);
    kb[0][t][1] = gload16(&Kh[(kbase + t * 16 + lc) * 64 + 32 + lg * 8]);
  }
  vmwait0();

  const f32x4 vzero = {0.f, 0.f, 0.f, 0.f};
  f32x4 accP[3][3];
#pragma unroll
  for (int qs = 0; qs < 3; ++qs)
#pragma unroll
    for (int dt = 0; dt < 3; ++dt) accP[qs][dt] = vzero;
  float lsum[3] = {0.f, 0.f, 0.f};
  bf16x8 pfrag[3] = {zer, zer, zer};

  const int bpA = (((lg & 1) * 32) + lc) * 4;
  const int bpB = bpA + 64;
  const bool hiK = lg >= 2;

#pragma unroll
  for (int kc = 0; kc < 9; ++kc) {
    const int cur = kc & 1;
    const int k0 = kbase + kc * 32;
    if (kc < 8) {
      const int k1 = k0 + 32;
#pragma unroll
      for (int t = 0; t < 2; ++t) {
        kb[cur ^ 1][t][0] = gload16(&Kh[(k1 + t * 16 + lc) * 64 + lg * 8]);
        kb[cur ^ 1][t][1] = gload16(&Kh[(k1 + t * 16 + lc) * 64 + 32 + lg * 8]);
      }
    }
    vb[cur][0] = gload16(&Vh[lc * 576 + k0 + lg * 8]);
    vb[cur][1] = gload16(&Vh[(16 + lc) * 576 + k0 + lg * 8]);
    vb[cur][2] = gload16(&Vh[(32 + lc) * 576 + k0 + lg * 8]);

    f32x4 s0[3], s1[3];
    __builtin_amdgcn_s_setprio(1);  // T5
#pragma unroll
    for (int qs = 0; qs < 3; ++qs) {
      f32x4 a = vzero, c = vzero;
      a = __builtin_amdgcn_mfma_f32_16x16x32_bf16(kb[cur][0][0], aq[qs][0], a, 0, 0, 0);
      a = __builtin_amdgcn_mfma_f32_16x16x32_bf16(kb[cur][0][1], aq[qs][1], a, 0, 0, 0);
      c = __builtin_amdgcn_mfma_f32_16x16x32_bf16(kb[cur][1][0], aq[qs][0], c, 0, 0, 0);
      c = __builtin_amdgcn_mfma_f32_16x16x32_bf16(kb[cur][1][1], aq[qs][1], c, 0, 0, 0);
      s0[qs] = a; s1[qs] = c;
    }
    if (kc > 0) {
#pragma unroll
      for (int qs = 0; qs < 3; ++qs) {
        accP[qs][0] = __builtin_amdgcn_mfma_f32_16x16x32_bf16(vb[cur ^ 1][0], pfrag[qs], accP[qs][0], 0, 0, 0);
        accP[qs][1] = __builtin_amdgcn_mfma_f32_16x16x32_bf16(vb[cur ^ 1][1], pfrag[qs], accP[qs][1], 0, 0, 0);
        accP[qs][2] = __builtin_amdgcn_mfma_f32_16x16x32_bf16(vb[cur ^ 1][2], pfrag[qs], accP[qs][2], 0, 0, 0);
      }
    }
    __builtin_amdgcn_s_setprio(0);

#pragma unroll
    for (int qs = 0; qs < 3; ++qs) {
      const float p00 = __expf(s0[qs][0]), p01 = __expf(s0[qs][1]);
      const float p02 = __expf(s0[qs][2]), p03 = __expf(s0[qs][3]);
      const float p10 = __expf(s1[qs][0]), p11 = __expf(s1[qs][1]);
      const float p12 = __expf(s1[qs][2]), p13 = __expf(s1[qs][3]);
      lsum[qs] += ((p00 + p01) + (p02 + p03)) + ((p10 + p11) + (p12 + p13));

      uint32_t c0, c1, d0, d1;
      asm("v_cvt_pk_bf16_f32 %0, %1, %2" : "=v"(c0) : "v"(p00), "v"(p01));
      asm("v_cvt_pk_bf16_f32 %0, %1, %2" : "=v"(c1) : "v"(p02), "v"(p03));
      asm("v_cvt_pk_bf16_f32 %0, %1, %2" : "=v"(d0) : "v"(p10), "v"(p11));
      asm("v_cvt_pk_bf16_f32 %0, %1, %2" : "=v"(d1) : "v"(p12), "v"(p13));

      const int a_c0 = __builtin_amdgcn_ds_bpermute(bpA, (int)c0);
      const int a_c1 = __builtin_amdgcn_ds_bpermute(bpA, (int)c1);
      const int a_d0 = __builtin_amdgcn_ds_bpermute(bpA, (int)d0);
      const int a_d1 = __builtin_amdgcn_ds_bpermute(bpA, (int)d1);
      const int b_c0 = __builtin_amdgcn_ds_bpermute(bpB, (int)c0);
      const int b_c1 = __builtin_amdgcn_ds_bpermute(bpB, (int)c1);
      const int b_d0 = __builtin_amdgcn_ds_bpermute(bpB, (int)d0);
      const int b_d1 = __builtin_amdgcn_ds_bpermute(bpB, (int)d1);
      union { uint32_t u[4]; bf16x8 v; } pf;
      pf.u[0] = hiK ? a_d0 : a_c0;
      pf.u[1] = hiK ? a_d1 : a_c1;
      pf.u[2] = hiK ? b_d0 : b_c0;
      pf.u[3] = hiK ? b_d1 : b_c1;
      pfrag[qs] = pf.v;
    }
    vmwait0();
  }
#pragma unroll
  for (int qs = 0; qs < 3; ++qs) {
    accP[qs][0] = __builtin_amdgcn_mfma_f32_16x16x32_bf16(vb[0][0], pfrag[qs], accP[qs][0], 0, 0, 0);
    accP[qs][1] = __builtin_amdgcn_mfma_f32_16x16x32_bf16(vb[0][1], pfrag[qs], accP[qs][1], 0, 0, 0);
    accP[qs][2] = __builtin_amdgcn_mfma_f32_16x16x32_bf16(vb[0][2], pfrag[qs], accP[qs][2], 0, 0, 0);
  }

  float ls[3];
#pragma unroll
  for (int qs = 0; qs < 3; ++qs) {
    float t = lsum[qs];
    t += __shfl_xor(t, 16, 64);
    t += __shfl_xor(t, 32, 64);
    ls[qs] = t;
  }

  if (ks == 1) {
#pragma unroll
    for (int qs = 0; qs < 3; ++qs) {
#pragma unroll
      for (int j = 0; j < 4; ++j) {
        red[(qh * 3 + qs) * 832 + lane * 13 + 0 + j] = accP[qs][0][j];
        red[(qh * 3 + qs) * 832 + lane * 13 + 4 + j] = accP[qs][1][j];
        red[(qh * 3 + qs) * 832 + lane * 13 + 8 + j] = accP[qs][2][j];
      }
      red[(qh * 3 + qs) * 832 + lane * 13 + 12] = ls[qs];
    }
  }
  __syncthreads();
  if (ks == 0) {
    const float g = 1.f / (1.f + __expf(-gating[h]));
#pragma unroll
    for (int qs = 0; qs < 3; ++qs) {
      const float* rr = &red[(qh * 3 + qs) * 832 + lane * 13];
      const float linv = (1.f - g) / (ls[qs] + rr[12]);
      const int row = b * 576 + qbase + qs * 16 + lc;
#pragma unroll
      for (int dt = 0; dt < 3; ++dt) {
        const f32x4 a = accP[qs][dt];
        const size_t idx = (size_t)row * 768 + h * 48 + dt * 16 + lg * 4;
        ushort4 o;
        if constexpr (RMW) {
          const ushort4 old4 = *(const ushort4*)&O[idx];
          o.x = f2bf((a[0] + rr[dt * 4 + 0]) * linv + bf2f(old4.x));
          o.y = f2bf((a[1] + rr[dt * 4 + 1]) * linv + bf2f(old4.y));
          o.z = f2bf((a[2] + rr[dt * 4 + 2]) * linv + bf2f(old4.z));
          o.w = f2bf((a[3] + rr[dt * 4 + 3]) * linv + bf2f(old4.w));
        } else {
          o.x = f2bf((a[0] + rr[dt * 4 + 0]) * linv);
          o.y = f2bf((a[1] + rr[dt * 4 + 1]) * linv);
          o.z = f2bf((a[2] + rr[dt * 4 + 2]) * linv);
          o.w = f2bf((a[3] + rr[dt * 4 + 3]) * linv);
        }
        *(ushort4*)&O[idx] = o;
      }
    }
  }
}

// Merged dispatch: blocks 0..767 = attn (writes O1), 768..1199 = pos_gemm (writes O2).
__global__ __launch_bounds__(256, 2) void pos_attn(
    const u16* __restrict__ Q, const u16* __restrict__ K, const u16* __restrict__ VT,
    const u16* __restrict__ posg, const float* __restrict__ gating,
    u16* __restrict__ O1, u16* __restrict__ O2) {
  __shared__ __align__(16) char smem[24576];
  if (blockIdx.x < 768)
    attn_body<false>(blockIdx.x, Q, K, VT, gating, O1, smem);
  else
    pos_gemm_body(blockIdx.x - 768, VT, posg, O2, smem);
}

// Fallback standalone kernels (ws too small for O1): serial path.
__global__ __launch_bounds__(256, 2) void pos_gemm_k(const u16* __restrict__ VT,
                                                     const u16* __restrict__ posg,
                                                     u16* __restrict__ O) {
  __shared__ __align__(16) char smem[24576];
  pos_gemm_body(blockIdx.x, VT, posg, O, smem);
}
__global__ __launch_bounds__(256, 2) void attn_rmw_k(
    const u16* __restrict__ Q, const u16* __restrict__ K, const u16* __restrict__ VT,
    const float* __restrict__ gating, u16* __restrict__ O) {
  __shared__ __align__(16) char smem[19968];
  attn_body<true>(blockIdx.x, Q, K, VT, gating, O, smem);
}

// ---------------- output projection: out = (B1 [+ B2]) @ Wproj^T + bias ----------------
template <bool SUM>
__global__ __launch_bounds__(256, 2) void gemm_proj(const u16* __restrict__ A,
                                                    const u16* __restrict__ B1,
                                                    const u16* __restrict__ B2,
                                                    float* __restrict__ of,
                                                    const float* __restrict__ bias) {
  __shared__ u16 sA[2][128 * 32];
  __shared__ u16 sB[2][64 * 32];

  const int mt = blockIdx.x / 72, nt = blockIdx.x % 72;
  const int mbase = mt * 128, nbase = nt * 64;
  const int tid = threadIdx.x;
  const int w = tid >> 6, lane = tid & 63;
  const int wr = w >> 1, wc = w & 1;
  const int lg = lane >> 4, lc = lane & 15;
  const int lgs = lg ^ ((lc >> 1) & 3);
  const int lrow = lane >> 2;
  const int lcol = (((lane & 3) ^ ((lane >> 3) & 3))) * 8;

  const u16* srcA0 = A + (size_t)(mbase + w * 16 + lrow) * 768 + lcol;
  const u16* srcA1 = srcA0 + (size_t)64 * 768;
  const size_t boff = (size_t)(nbase + w * 16 + lrow) * 768 + lcol;
  const u16* srcB1 = B1 + boff;
  const u16* srcB2 = B2 + boff;
  const int dof = w * 512;
  const int wof = dof + lrow * 32 + (lane & 3) * 8;  // linear dest slot (matches gl_lds layout)

  const f32x4 vzero = {0.f, 0.f, 0.f, 0.f};
  f32x4 acc[4][2];
#pragma unroll
  for (int i = 0; i < 4; ++i)
#pragma unroll
    for (int j = 0; j < 2; ++j) acc[i][j] = vzero;

  if constexpr (SUM) {
    const bf16x8 rb1 = *(const bf16x8*)srcB1;
    const bf16x8 rb2 = *(const bf16x8*)srcB2;
    gl_lds16(srcA0, sA[0] + dof);
    gl_lds16(srcA1, sA[0] + 2048 + dof);
    bf16x8 rs;
#pragma unroll
    for (int e = 0; e < 8; ++e) rs[e] = (short)f2bf(bf2f((u16)rb1[e]) + bf2f((u16)rb2[e]));
    *(bf16x8*)&sB[0][wof] = rs;
  } else {
    gl_lds16(srcA0, sA[0] + dof);
    gl_lds16(srcA1, sA[0] + 2048 + dof);
    gl_lds16(srcB1, sB[0] + dof);
  }
  __syncthreads();

  int buf = 0;
  for (int kt = 0; kt < 24; ++kt) {
    const int nb = buf ^ 1;
    bf16x8 rb1, rb2;
    if (kt < 23) {
      const int kb = (kt + 1) * 32;
      if constexpr (SUM) {
        rb1 = *(const bf16x8*)(srcB1 + kb);
        rb2 = *(const bf16x8*)(srcB2 + kb);
      }
      gl_lds16(srcA0 + kb, sA[nb] + dof);
      gl_lds16(srcA1 + kb, sA[nb] + 2048 + dof);
      if constexpr (!SUM) gl_lds16(srcB1 + kb, sB[nb] + dof);
    }
    bf16x8 av[4], bv[2];
#pragma unroll
    for (int i = 0; i < 4; ++i)
      av[i] = *(const bf16x8*)&sA[buf][(wr * 64 + i * 16 + lc) * 32 + lgs * 8];
#pragma unroll
    for (int jn = 0; jn < 2; ++jn)
      bv[jn] = *(const bf16x8*)&sB[buf][(wc * 32 + jn * 16 + lc) * 32 + lgs * 8];
#pragma unroll
    for (int i = 0; i < 4; ++i)
#pragma unroll
      for (int jn = 0; jn < 2; ++jn)
        acc[i][jn] = __builtin_amdgcn_mfma_f32_16x16x32_bf16(av[i], bv[jn], acc[i][jn], 0, 0, 0);
    if constexpr (SUM) {
      if (kt < 23) {
        bf16x8 rs;
#pragma unroll
        for (int e = 0; e < 8; ++e) rs[e] = (short)f2bf(bf2f((u16)rb1[e]) + bf2f((u16)rb2[e]));
        *(bf16x8*)&sB[nb][wof] = rs;
      }
    }
    __syncthreads();
    buf = nb;
  }

#pragma unroll
  for (int i = 0; i < 4; ++i) {
    const int c0 = mbase + wr * 64 + i * 16 + lg * 4;
    const float4 b4 = *(const float4*)&bias[c0];
#pragma unroll
    for (int jn = 0; jn < 2; ++jn) {
      const int bn = nbase + wc * 32 + jn * 16 + lc;
      float4 o;
      o.x = acc[i][jn][0] + b4.x; o.y = acc[i][jn][1] + b4.y;
      o.z = acc[i][jn][2] + b4.z; o.w = acc[i][jn][3] + b4.w;
      *(float4*)&of[(size_t)bn * 768 + c0] = o;
    }
  }
}

// ---------------- launch ----------------
extern "C" void kernel_launch(void* const* d_in, const int* in_sizes, int n_in,
                              void* d_out, int out_size, void* d_ws, size_t ws_size,
                              hipStream_t stream) {
  const float* x      = (const float*)d_in[0];
  const float* Wq     = (const float*)d_in[1];
  const float* Wk     = (const float*)d_in[2];
  const float* Wv     = (const float*)d_in[3];
  const float* Wp     = (const float*)d_in[4];
  const float* bproj  = (const float*)d_in[5];
  const float* Wpos   = (const float*)d_in[6];
  const float* bpos   = (const float*)d_in[7];
  const float* gating = (const float*)d_in[8];
  float* out = (float*)d_out;

  char* ws = (char*)d_ws;
  u16* xb      = (u16*)(ws + 0);
  u16* wqb     = (u16*)(ws + 7077888);
  u16* wkb     = (u16*)(ws + 8257536);
  u16* wvb     = (u16*)(ws + 9437184);
  u16* wpb     = (u16*)(ws + 10616832);
  u16* Qw      = (u16*)(ws + 11796480);
  u16* Kw      = (u16*)(ws + 21233664);
  u16* VTw     = (u16*)(ws + 30670848);
  u16* O2w     = (u16*)(ws + 37748736);
  u16* O1w     = (u16*)(ws + 44826624);   // merged-attn path only
  u16* posg_hi = (u16*)(ws + 51904512);   // fresh posg (no overlay), high tier only
  u16* posg_lo = (u16*)(ws + 0);          // overlay (xb..wvb) — ONLY written after gemm_qkv

  const bool big   = ws_size >= (size_t)62521344;  // posg_hi fits
  const bool merge = ws_size >= (size_t)51904512;  // O1 fits

  if (big) {
    // posg computed up-front into fresh space (no clobber of xb/weights)
    cvt_pos<<<dim3(8064), dim3(256), 0, stream>>>(x, Wq, Wk, Wv, Wp, xb, Wpos, bpos, gating,
                                                  posg_hi);
    gemm_qkv<<<dim3(216, 3), dim3(256), 0, stream>>>(wqb, wkb, wvb, xb, Qw, Kw, VTw);
    pos_attn<<<dim3(1200), dim3(256), 0, stream>>>(Qw, Kw, VTw, posg_hi, gating, O1w, O2w);
    gemm_proj<true><<<dim3(432), dim3(256), 0, stream>>>(wpb, O1w, O2w, out, bproj);
  } else {
    // posg overlays xb/weights -> MUST be written only after gemm_qkv consumed them
    cvt_pos<<<dim3(5760), dim3(256), 0, stream>>>(x, Wq, Wk, Wv, Wp, xb, Wpos, bpos, gating,
                                                  posg_lo);
    gemm_qkv<<<dim3(216, 3), dim3(256), 0, stream>>>(wqb, wkb, wvb, xb, Qw, Kw, VTw);
    pos_soft<<<dim3(2304), dim3(256), 0, stream>>>(Wpos, bpos, gating, posg_lo);
    if (merge) {
      pos_attn<<<dim3(1200), dim3(256), 0, stream>>>(Qw, Kw, VTw, posg_lo, gating, O1w, O2w);
      gemm_proj<true><<<dim3(432), dim3(256), 0, stream>>>(wpb, O1w, O2w, out, bproj);
    } else {
      pos_gemm_k<<<dim3(432), dim3(256), 0, stream>>>(VTw, posg_lo, O2w);
      attn_rmw_k<<<dim3(768), dim3(256), 0, stream>>>(Qw, Kw, VTw, gating, O2w);
      gemm_proj<false><<<dim3(432), dim3(256), 0, stream>>>(wpb, O2w, O2w, out, bproj);
    }
  }
}